// Round 2
// 401.011 us; speedup vs baseline: 1.0426x; 1.0426x over previous
//
#include <hip/hip_runtime.h>
#include <hip/hip_bf16.h>

#define NNODES 100000
#define NEDGES 1600000
#define DF 128
#define NC 40
#define NCP 48          // padded fc cols (3 x 16)
#define NB 196          // CSR bins: dst>>9, 512 nodes/bin
#define CH 4096         // edges per binscatter/bincount block
#define GEMM_BLOCKS 512 // persistent: 2 blocks/CU x 256 CU
#define GEMM_WAVES (GEMM_BLOCKS * 4)

typedef __bf16 bf16x8 __attribute__((ext_vector_type(8)));
typedef float f32x4 __attribute__((ext_vector_type(4)));

__device__ __forceinline__ unsigned short f2bf(float f) {
    unsigned int u = __builtin_bit_cast(unsigned int, f);
    u = (u + 0x7FFFu + ((u >> 16) & 1u)) >> 16;   // RNE
    return (unsigned short)u;
}
__device__ __forceinline__ float bf2f(unsigned short s) {
    unsigned int u = ((unsigned int)s) << 16;
    return __builtin_bit_cast(float, u);
}
__device__ __forceinline__ float bfLo(unsigned int u) {
    return __builtin_bit_cast(float, u << 16);
}
__device__ __forceinline__ float bfHi(unsigned int u) {
    return __builtin_bit_cast(float, u & 0xFFFF0000u);
}

// ---------------- dtype detection (flags[0]: ei is int64; flags[1]: floats are bf16)
__global__ void k_detect(const unsigned int* __restrict__ ei32,
                         const unsigned int* __restrict__ x32,
                         int* __restrict__ flags) {
    __shared__ unsigned int rOr[256];
    __shared__ int rCnt[256];
    unsigned int o = 0; int c = 0;
    for (int i = threadIdx.x; i < 1024; i += 256) o |= ei32[2 * i + 1];
    for (int i = threadIdx.x; i < 4096; i += 256) {
        unsigned int e = (x32[i] >> 7) & 0xFFu;
        c += (e >= 100u && e <= 140u) ? 1 : 0;
    }
    rOr[threadIdx.x] = o; rCnt[threadIdx.x] = c;
    __syncthreads();
    for (int s = 128; s; s >>= 1) {
        if ((int)threadIdx.x < s) {
            rOr[threadIdx.x] |= rOr[threadIdx.x + s];
            rCnt[threadIdx.x] += rCnt[threadIdx.x + s];
        }
        __syncthreads();
    }
    if (threadIdx.x == 0) {
        flags[0] = (rOr[0] == 0u) ? 1 : 0;
        flags[1] = (rCnt[0] > 2457) ? 1 : 0;
    }
}

__device__ __forceinline__ int ldIdx(const void* ei, int flag64, int i) {
    return flag64 ? (int)((const long long*)ei)[i] : ((const int*)ei)[i];
}

// ---------------- features -> canonical bf16
__global__ __launch_bounds__(256) void k_cvt_feat(const void* __restrict__ src,
                                                  const int* __restrict__ flags,
                                                  unsigned short* __restrict__ dst, int n) {
    int i = blockIdx.x * 256 + threadIdx.x;
    if (i >= n) return;
    dst[i] = flags[1] ? ((const unsigned short*)src)[i]
                      : f2bf(((const float*)src)[i]);
}

// ---------------- all weights (transposed bf16) + biases (fp32) in ONE launch.
__global__ __launch_bounds__(256) void k_wprep(const void* w1a, const void* w1b,
                                               const void* w2a, const void* w2b,
                                               const void* wfc,
                                               const void* b1a, const void* b1b,
                                               const void* b2a, const void* b2b,
                                               const void* bfc,
                                               const int* __restrict__ flags,
                                               unsigned short* __restrict__ wAll,
                                               float* __restrict__ bAll) {
    int idx = blockIdx.x * 256 + threadIdx.x;
    int bf = flags[1];
    auto ldf = [&](const void* p, int i) -> float {
        return bf ? bf2f(((const unsigned short*)p)[i]) : ((const float*)p)[i];
    };
    if (idx < 65536) {                       // 4 square transposes
        int wi = idx >> 14, r = idx & 16383;
        int n = r >> 7, k = r & 127;
        const void* s = (wi == 0) ? w1a : (wi == 1) ? w1b : (wi == 2) ? w2a : w2b;
        wAll[idx] = f2bf(ldf(s, k * 128 + n));
    } else if (idx < 65536 + NCP * 128) {    // wfc transpose, zero pad
        int r = idx - 65536;
        int n = r >> 7, k = r & 127;
        wAll[idx] = (n < NC) ? f2bf(ldf(wfc, k * NC + n)) : (unsigned short)0;
    } else if (idx < 65536 + NCP * 128 + 512 + NC) {
        int r = idx - (65536 + NCP * 128);
        const void* s; int i;
        if (r < 128)      { s = b1a; i = r; }
        else if (r < 256) { s = b1b; i = r - 128; }
        else if (r < 384) { s = b2a; i = r - 256; }
        else if (r < 512) { s = b2b; i = r - 384; }
        else              { s = bfc; i = r - 512; }
        bAll[r] = ldf(s, i);
    }
}

// ================= binned CSR build =================
__global__ __launch_bounds__(256) void k_bincount(const void* __restrict__ ei,
                                                  const int* __restrict__ flags,
                                                  int* __restrict__ binCnt) {
    __shared__ int l[NB];
    int t = threadIdx.x;
    int f64 = flags[0];
    for (int i = t; i < NB; i += 256) l[i] = 0;
    __syncthreads();
    int base = blockIdx.x * CH;
#pragma unroll
    for (int k = 0; k < CH / 256; k++) {
        int e = base + k * 256 + t;
        if (e < NEDGES) atomicAdd(&l[ldIdx(ei, f64, NEDGES + e) >> 9], 1);
    }
    __syncthreads();
    for (int i = t; i < NB; i += 256)
        if (l[i]) atomicAdd(&binCnt[i], l[i]);
}

__global__ __launch_bounds__(256) void k_binscan(const int* __restrict__ binCnt,
                                                 int* __restrict__ binOfs,
                                                 int* __restrict__ binCur) {
    __shared__ int sh[256];
    int t = threadIdx.x;
    int v = (t < NB) ? binCnt[t] : 0;
    sh[t] = v;
    __syncthreads();
    for (int off = 1; off < 256; off <<= 1) {
        int x = (t >= off) ? sh[t - off] : 0;
        __syncthreads();
        sh[t] += x;
        __syncthreads();
    }
    if (t < NB) {
        binOfs[t + 1] = sh[t];
        binCur[t] = sh[t] - v;      // exclusive
    }
    if (t == 0) binOfs[0] = 0;
}

__global__ __launch_bounds__(256) void k_binscatter(const void* __restrict__ ei,
                                                    const int* __restrict__ flags,
                                                    int* __restrict__ binCur,
                                                    int2* __restrict__ ebin) {
    __shared__ int lcnt[NB], lbase[NB], lofs[NB];
    int t = threadIdx.x;
    int f64 = flags[0];
    for (int i = t; i < NB; i += 256) lcnt[i] = 0;
    __syncthreads();
    int base = blockIdx.x * CH;
    int2 ed[CH / 256];
    int bn[CH / 256];
#pragma unroll
    for (int k = 0; k < CH / 256; k++) {
        int e = base + k * 256 + t;
        if (e < NEDGES) {
            ed[k].x = ldIdx(ei, f64, e);
            ed[k].y = ldIdx(ei, f64, NEDGES + e);
            bn[k] = ed[k].y >> 9;
            atomicAdd(&lcnt[bn[k]], 1);
        } else bn[k] = -1;
    }
    __syncthreads();
    if (t < NB) {
        int c = lcnt[t];
        lbase[t] = c ? atomicAdd(&binCur[t], c) : 0;
        lofs[t] = 0;
    }
    __syncthreads();
#pragma unroll
    for (int k = 0; k < CH / 256; k++) {
        if (bn[k] >= 0) {
            int p = lbase[bn[k]] + atomicAdd(&lofs[bn[k]], 1);
            ebin[p] = ed[k];
        }
    }
}

__global__ __launch_bounds__(256) void k_binfill(const int2* __restrict__ ebin,
                                                 const int* __restrict__ binOfs,
                                                 int* __restrict__ rowptr,
                                                 int* __restrict__ perm) {
    __shared__ int deg[512], lptr[512], ssum[256];
    int b = blockIdx.x, t = threadIdx.x;
    int n0 = b << 9;
    int nn = NNODES - n0; if (nn > 512) nn = 512;
    int e0 = binOfs[b], e1 = binOfs[b + 1];
    deg[t] = 0; deg[t + 256] = 0;
    __syncthreads();
    for (int e = e0 + t; e < e1; e += 256)
        atomicAdd(&deg[ebin[e].y - n0], 1);
    __syncthreads();
    int d0 = deg[2 * t], d1 = deg[2 * t + 1];
    int s = d0 + d1;
    ssum[t] = s;
    __syncthreads();
    for (int off = 1; off < 256; off <<= 1) {
        int x = (t >= off) ? ssum[t - off] : 0;
        __syncthreads();
        ssum[t] += x;
        __syncthreads();
    }
    int ex = ssum[t] - s;
    lptr[2 * t] = ex;
    lptr[2 * t + 1] = ex + d0;
    if (2 * t < nn)     rowptr[n0 + 2 * t] = e0 + ex;
    if (2 * t + 1 < nn) rowptr[n0 + 2 * t + 1] = e0 + ex + d0;
    if (b == NB - 1 && t == 0) rowptr[NNODES] = e1;
    deg[2 * t] = 0; deg[2 * t + 1] = 0;   // reuse as cursor
    __syncthreads();
    for (int e = e0 + t; e < e1; e += 256) {
        int2 ed = ebin[e];
        int d = ed.y - n0;
        int pos = e0 + lptr[d] + atomicAdd(&deg[d], 1);
        perm[pos] = ed.x;
    }
}

// ================= gather aggregation =================
// One node per wave; 4 groups of 16 lanes each process one edge per load:
// lane (g=lane>>4, c=lane&15) loads dwordx4 (16B) at feat[src]*256 + c*16.
// 4x fewer VMEM instrs per edge than the dword version; 16-edge main stage
// keeps 4KB/wave of loads in flight. Cross-group combine: shfl_xor 16,32.
__device__ __forceinline__ void acc8(float* acc, uint4 u) {
    acc[0] += bfLo(u.x); acc[1] += bfHi(u.x);
    acc[2] += bfLo(u.y); acc[3] += bfHi(u.y);
    acc[4] += bfLo(u.z); acc[5] += bfHi(u.z);
    acc[6] += bfLo(u.w); acc[7] += bfHi(u.w);
}

__global__ __launch_bounds__(256) void k_gather(const unsigned short* __restrict__ feat,
                                                const unsigned short* __restrict__ x,
                                                const int* __restrict__ rowptr,
                                                const int* __restrict__ perm,
                                                unsigned short* __restrict__ out) {
    int wave = threadIdx.x >> 6, lane = threadIdx.x & 63;
    int i = blockIdx.x * 4 + wave;        // NNODES = 25000*4 exactly
    int g = lane >> 4, c = lane & 15;
    const uint4* F = (const uint4*)feat;  // one row = 16 uint4
    float acc[8];
#pragma unroll
    for (int k = 0; k < 8; k++) acc[k] = 0.f;

    int jb = rowptr[i], je = rowptr[i + 1];
    int j = jb;
    // 16 edges per iteration: 4 perm dwords + 4 feature dwordx4 in flight
    for (; j + 16 <= je; j += 16) {
        int s0 = perm[j + g], s1 = perm[j + 4 + g];
        int s2 = perm[j + 8 + g], s3 = perm[j + 12 + g];
        uint4 u0 = F[s0 * 16 + c];
        uint4 u1 = F[s1 * 16 + c];
        uint4 u2 = F[s2 * 16 + c];
        uint4 u3 = F[s3 * 16 + c];
        acc8(acc, u0); acc8(acc, u1); acc8(acc, u2); acc8(acc, u3);
    }
    // 8-edge stage
    if (j + 8 <= je) {
        int s0 = perm[j + g], s1 = perm[j + 4 + g];
        uint4 u0 = F[s0 * 16 + c];
        uint4 u1 = F[s1 * 16 + c];
        acc8(acc, u0); acc8(acc, u1);
        j += 8;
    }
    // tail: up to 7 edges, per-group predicated
    if (j < je) {
        int e0 = j + g, e1 = j + 4 + g;
        int s0 = perm[e0 < je ? e0 : jb];
        int s1 = perm[e1 < je ? e1 : jb];
        uint4 u0 = F[s0 * 16 + c];
        uint4 u1 = F[s1 * 16 + c];
        if (e0 < je) acc8(acc, u0);
        if (e1 < je) acc8(acc, u1);
    }

    // combine the 4 group partials (feature layout identical across groups)
#pragma unroll
    for (int k = 0; k < 8; k++) {
        acc[k] += __shfl_xor(acc[k], 16);
        acc[k] += __shfl_xor(acc[k], 32);
    }

    // h = x + agg
    uint4 xv = ((const uint4*)x)[i * 16 + c];
    acc[0] += bfLo(xv.x); acc[1] += bfHi(xv.x);
    acc[2] += bfLo(xv.y); acc[3] += bfHi(xv.y);
    acc[4] += bfLo(xv.z); acc[5] += bfHi(xv.z);
    acc[6] += bfLo(xv.w); acc[7] += bfHi(xv.w);

    if (g == 0) {
        uint4 r;
        r.x = ((unsigned int)f2bf(acc[1]) << 16) | f2bf(acc[0]);
        r.y = ((unsigned int)f2bf(acc[3]) << 16) | f2bf(acc[2]);
        r.z = ((unsigned int)f2bf(acc[5]) << 16) | f2bf(acc[4]);
        r.w = ((unsigned int)f2bf(acc[7]) << 16) | f2bf(acc[6]);
        ((uint4*)out)[i * 16 + c] = r;
    }
}

// ---------------- persistent register-resident-B GEMM: C = relu(A@W + bias).
// 2048 waves grid-stride 6250 row-tiles (~3 each). W (128 VGPR) + bias loaded
// ONCE per wave; per tile: 4 A-loads (b128) + 32 MFMA + stores. Independent
// iterations let the compiler pipeline next-tile A-loads under MFMAs.
// Layouts (m89/m91): A[m=lane&15][k=quad*8+j]; B[k=quad*8+j][n=lane&15];
// D: col=lane&15, row=quad*4+reg.
__global__ __launch_bounds__(256, 2) void k_gemm_rb(const unsigned short* __restrict__ A,
                                                    const unsigned short* __restrict__ WT,
                                                    const float* __restrict__ bias,
                                                    unsigned short* __restrict__ out) {
    int gw = blockIdx.x * 4 + (threadIdx.x >> 6);   // global wave id
    int lane = threadIdx.x & 63;
    int m = lane & 15, quad = lane >> 4;

    bf16x8 bfr[8][4];
#pragma unroll
    for (int nt = 0; nt < 8; nt++) {
        const unsigned short* Bb = WT + (nt * 16 + m) * DF + quad * 8;
#pragma unroll
        for (int ks = 0; ks < 4; ks++)
            bfr[nt][ks] = *(const bf16x8*)(Bb + ks * 32);
    }
    float bv[8];
#pragma unroll
    for (int nt = 0; nt < 8; nt++) bv[nt] = bias[nt * 16 + m];

    for (int tile = gw; tile < NNODES / 16; tile += GEMM_WAVES) {
        int r0 = tile * 16;
        const unsigned short* Ab = A + (r0 + m) * DF + quad * 8;
        bf16x8 a[4];
#pragma unroll
        for (int ks = 0; ks < 4; ks++) a[ks] = *(const bf16x8*)(Ab + ks * 32);

        f32x4 acc[8];
#pragma unroll
        for (int nt = 0; nt < 8; nt++) acc[nt] = (f32x4){0.f, 0.f, 0.f, 0.f};
#pragma unroll
        for (int nt = 0; nt < 8; nt++)
#pragma unroll
            for (int ks = 0; ks < 4; ks++)
                acc[nt] = __builtin_amdgcn_mfma_f32_16x16x32_bf16(a[ks], bfr[nt][ks], acc[nt], 0, 0, 0);

#pragma unroll
        for (int nt = 0; nt < 8; nt++) {
            int col = nt * 16 + m;
#pragma unroll
            for (int reg = 0; reg < 4; reg++) {
                int row = r0 + quad * 4 + reg;
                float v = acc[nt][reg] + bv[nt];
                if (v < 0.f) v = 0.f;
                out[row * DF + col] = f2bf(v);
            }
        }
    }
}

// ---------------- persistent fc (128 -> 40, padded 48) + fused log_softmax.
__global__ __launch_bounds__(256, 2) void k_fc_rb(const unsigned short* __restrict__ A,
                                                  const unsigned short* __restrict__ WfcT,
                                                  const float* __restrict__ bfc,
                                                  const int* __restrict__ flags,
                                                  void* __restrict__ out) {
    int gw = blockIdx.x * 4 + (threadIdx.x >> 6);
    int lane = threadIdx.x & 63;
    int m = lane & 15, quad = lane >> 4;
    bool valid2 = (m < 8);
    int obf = flags[1];

    bf16x8 bfr[3][4];
#pragma unroll
    for (int nt = 0; nt < 3; nt++) {
        const unsigned short* Bb = WfcT + (nt * 16 + m) * DF + quad * 8;
#pragma unroll
        for (int ks = 0; ks < 4; ks++)
            bfr[nt][ks] = *(const bf16x8*)(Bb + ks * 32);
    }
    float bv0 = bfc[m], bv1 = bfc[16 + m];
    float bv2 = valid2 ? bfc[32 + m] : 0.f;

    for (int tile = gw; tile < NNODES / 16; tile += GEMM_WAVES) {
        int r0 = tile * 16;
        const unsigned short* Ab = A + (r0 + m) * DF + quad * 8;
        bf16x8 a[4];
#pragma unroll
        for (int ks = 0; ks < 4; ks++) a[ks] = *(const bf16x8*)(Ab + ks * 32);

        f32x4 acc[3];
#pragma unroll
        for (int nt = 0; nt < 3; nt++) acc[nt] = (f32x4){0.f, 0.f, 0.f, 0.f};
#pragma unroll
        for (int nt = 0; nt < 3; nt++)
#pragma unroll
            for (int ks = 0; ks < 4; ks++)
                acc[nt] = __builtin_amdgcn_mfma_f32_16x16x32_bf16(a[ks], bfr[nt][ks], acc[nt], 0, 0, 0);

#pragma unroll
        for (int reg = 0; reg < 4; reg++) {
            float v0 = acc[0][reg] + bv0;
            float v1 = acc[1][reg] + bv1;
            float v2 = valid2 ? (acc[2][reg] + bv2) : -3.0e38f;
            float mx = fmaxf(fmaxf(v0, v1), v2);
#pragma unroll
            for (int off = 1; off < 16; off <<= 1) mx = fmaxf(mx, __shfl_xor(mx, off, 16));
            float e = __expf(v0 - mx) + __expf(v1 - mx) + (valid2 ? __expf(v2 - mx) : 0.f);
#pragma unroll
            for (int off = 1; off < 16; off <<= 1) e += __shfl_xor(e, off, 16);
            float l = mx + __logf(e);
            int row = r0 + quad * 4 + reg;
            if (obf) {
                unsigned short* o = (unsigned short*)out + row * NC;
                o[m] = f2bf(v0 - l);
                o[16 + m] = f2bf(v1 - l);
                if (valid2) o[32 + m] = f2bf(v2 - l);
            } else {
                float* o = (float*)out + row * NC;
                o[m] = v0 - l;
                o[16 + m] = v1 - l;
                if (valid2) o[32 + m] = v2 - l;
            }
        }
    }
}

extern "C" void kernel_launch(void* const* d_in, const int* in_sizes, int n_in,
                              void* d_out, int out_size, void* d_ws, size_t ws_size,
                              hipStream_t stream) {
    const void* x   = d_in[0];
    const void* ei  = d_in[1];
    const void* w1a = d_in[2];
    const void* b1a = d_in[3];
    const void* w1b = d_in[4];
    const void* b1b = d_in[5];
    const void* w2a = d_in[6];
    const void* b2a = d_in[7];
    const void* w2b = d_in[8];
    const void* b2b = d_in[9];
    const void* wfc = d_in[10];
    const void* bfc = d_in[11];

    char* ws = (char*)d_ws;
    size_t off = 0;
    auto alloc = [&](size_t bytes) {
        void* p = ws + off;
        off += (bytes + 255) & ~(size_t)255;
        return p;
    };
    unsigned short* B0    = (unsigned short*)alloc((size_t)NNODES * DF * 2);
    unsigned short* B1    = (unsigned short*)alloc((size_t)NNODES * DF * 2);
    unsigned short* B2    = (unsigned short*)alloc((size_t)NNODES * DF * 2);
    int2*           ebin  = (int2*)alloc((size_t)NEDGES * 8);
    int*            perm  = (int*)alloc((size_t)NEDGES * 4);
    int*            rowptr= (int*)alloc((size_t)(NNODES + 1) * 4);
    int*            binCnt= (int*)alloc(NB * 4);
    int*            binOfs= (int*)alloc((NB + 1) * 4);
    int*            binCur= (int*)alloc(NB * 4);
    int*            flags = (int*)alloc(256);
    unsigned short* wAll  = (unsigned short*)alloc((4 * 16384 + NCP * 128) * 2);
    float*          bAll  = (float*)alloc((512 + NC) * 4);

    unsigned short* w1aT = wAll;
    unsigned short* w1bT = wAll + 16384;
    unsigned short* w2aT = wAll + 32768;
    unsigned short* w2bT = wAll + 49152;
    unsigned short* wfcT = wAll + 65536;
    float* b1af = bAll;
    float* b1bf = bAll + 128;
    float* b2af = bAll + 256;
    float* b2bf = bAll + 384;
    float* bfcf = bAll + 512;

    // ---- dtype detection + canonicalization
    k_detect<<<1, 256, 0, stream>>>((const unsigned int*)ei, (const unsigned int*)x, flags);
    k_cvt_feat<<<(NNODES * DF + 255) / 256, 256, 0, stream>>>(x, flags, B0, NNODES * DF);

    int wprepN = 4 * 16384 + NCP * 128 + 512 + NC;
    k_wprep<<<(wprepN + 255) / 256, 256, 0, stream>>>(w1a, w1b, w2a, w2b, wfc,
                                                      b1a, b1b, b2a, b2b, bfc,
                                                      flags, wAll, bAll);

    // ---- binned CSR build (reads edge_index directly)
    hipMemsetAsync(binCnt, 0, NB * 4, stream);
    int nEB = (NEDGES + CH - 1) / CH;                          // 391
    k_bincount<<<nEB, 256, 0, stream>>>(ei, flags, binCnt);
    k_binscan<<<1, 256, 0, stream>>>(binCnt, binOfs, binCur);
    k_binscatter<<<nEB, 256, 0, stream>>>(ei, flags, binCur, ebin);
    k_binfill<<<NB, 256, 0, stream>>>(ebin, binOfs, rowptr, perm);

    const int gatherGrid = NNODES / 4;                         // 25000

    // ---- layer 1
    k_gather<<<gatherGrid, 256, 0, stream>>>(B0, B0, rowptr, perm, B1);
    k_gemm_rb<<<GEMM_BLOCKS, 256, 0, stream>>>(B1, w1aT, b1af, B2);
    k_gemm_rb<<<GEMM_BLOCKS, 256, 0, stream>>>(B2, w1bT, b1bf, B1);   // h1 -> B1

    // ---- layer 2
    k_gather<<<gatherGrid, 256, 0, stream>>>(B1, B1, rowptr, perm, B2);
    k_gemm_rb<<<GEMM_BLOCKS, 256, 0, stream>>>(B2, w2aT, b2af, B0);
    k_gemm_rb<<<GEMM_BLOCKS, 256, 0, stream>>>(B0, w2bT, b2bf, B2);   // h2 -> B2

    // ---- fc + log_softmax
    k_fc_rb<<<GEMM_BLOCKS, 256, 0, stream>>>(B2, wfcT, bfcf, flags, d_out);
}

// Round 3
// 394.944 us; speedup vs baseline: 1.0586x; 1.0154x over previous
//
#include <hip/hip_runtime.h>
#include <hip/hip_bf16.h>

#define NNODES 100000
#define NEDGES 1600000
#define DF 128
#define NC 40
#define NCP 48          // padded fc cols (3 x 16)
#define NB 196          // CSR bins: dst>>9, 512 nodes/bin
#define CH 4096         // edges per binscatter/bincount block
#define GEMM_BLOCKS 512 // persistent: 2 blocks/CU x 256 CU
#define GEMM_WAVES (GEMM_BLOCKS * 4)

typedef __bf16 bf16x8 __attribute__((ext_vector_type(8)));
typedef float f32x4 __attribute__((ext_vector_type(4)));

__device__ __forceinline__ unsigned short f2bf(float f) {
    unsigned int u = __builtin_bit_cast(unsigned int, f);
    u = (u + 0x7FFFu + ((u >> 16) & 1u)) >> 16;   // RNE
    return (unsigned short)u;
}
__device__ __forceinline__ float bf2f(unsigned short s) {
    unsigned int u = ((unsigned int)s) << 16;
    return __builtin_bit_cast(float, u);
}
__device__ __forceinline__ float bfLo(unsigned int u) {
    return __builtin_bit_cast(float, u << 16);
}
__device__ __forceinline__ float bfHi(unsigned int u) {
    return __builtin_bit_cast(float, u & 0xFFFF0000u);
}

// ---------------- dtype detection (flags[0]: ei is int64; flags[1]: floats are bf16)
__global__ void k_detect(const unsigned int* __restrict__ ei32,
                         const unsigned int* __restrict__ x32,
                         int* __restrict__ flags) {
    __shared__ unsigned int rOr[256];
    __shared__ int rCnt[256];
    unsigned int o = 0; int c = 0;
    for (int i = threadIdx.x; i < 1024; i += 256) o |= ei32[2 * i + 1];
    for (int i = threadIdx.x; i < 4096; i += 256) {
        unsigned int e = (x32[i] >> 7) & 0xFFu;
        c += (e >= 100u && e <= 140u) ? 1 : 0;
    }
    rOr[threadIdx.x] = o; rCnt[threadIdx.x] = c;
    __syncthreads();
    for (int s = 128; s; s >>= 1) {
        if ((int)threadIdx.x < s) {
            rOr[threadIdx.x] |= rOr[threadIdx.x + s];
            rCnt[threadIdx.x] += rCnt[threadIdx.x + s];
        }
        __syncthreads();
    }
    if (threadIdx.x == 0) {
        flags[0] = (rOr[0] == 0u) ? 1 : 0;
        flags[1] = (rCnt[0] > 2457) ? 1 : 0;
    }
}

__device__ __forceinline__ int ldIdx(const void* ei, int flag64, int i) {
    return flag64 ? (int)((const long long*)ei)[i] : ((const int*)ei)[i];
}

// ---------------- features -> canonical bf16
__global__ __launch_bounds__(256) void k_cvt_feat(const void* __restrict__ src,
                                                  const int* __restrict__ flags,
                                                  unsigned short* __restrict__ dst, int n) {
    int i = blockIdx.x * 256 + threadIdx.x;
    if (i >= n) return;
    dst[i] = flags[1] ? ((const unsigned short*)src)[i]
                      : f2bf(((const float*)src)[i]);
}

// ---------------- all weights (transposed bf16) + biases (fp32) in ONE launch.
__global__ __launch_bounds__(256) void k_wprep(const void* w1a, const void* w1b,
                                               const void* w2a, const void* w2b,
                                               const void* wfc,
                                               const void* b1a, const void* b1b,
                                               const void* b2a, const void* b2b,
                                               const void* bfc,
                                               const int* __restrict__ flags,
                                               unsigned short* __restrict__ wAll,
                                               float* __restrict__ bAll) {
    int idx = blockIdx.x * 256 + threadIdx.x;
    int bf = flags[1];
    auto ldf = [&](const void* p, int i) -> float {
        return bf ? bf2f(((const unsigned short*)p)[i]) : ((const float*)p)[i];
    };
    if (idx < 65536) {                       // 4 square transposes
        int wi = idx >> 14, r = idx & 16383;
        int n = r >> 7, k = r & 127;
        const void* s = (wi == 0) ? w1a : (wi == 1) ? w1b : (wi == 2) ? w2a : w2b;
        wAll[idx] = f2bf(ldf(s, k * 128 + n));
    } else if (idx < 65536 + NCP * 128) {    // wfc transpose, zero pad
        int r = idx - 65536;
        int n = r >> 7, k = r & 127;
        wAll[idx] = (n < NC) ? f2bf(ldf(wfc, k * NC + n)) : (unsigned short)0;
    } else if (idx < 65536 + NCP * 128 + 512 + NC) {
        int r = idx - (65536 + NCP * 128);
        const void* s; int i;
        if (r < 128)      { s = b1a; i = r; }
        else if (r < 256) { s = b1b; i = r - 128; }
        else if (r < 384) { s = b2a; i = r - 256; }
        else if (r < 512) { s = b2b; i = r - 384; }
        else              { s = bfc; i = r - 512; }
        bAll[r] = ldf(s, i);
    }
}

// ================= binned CSR build =================
__global__ __launch_bounds__(256) void k_bincount(const void* __restrict__ ei,
                                                  const int* __restrict__ flags,
                                                  int* __restrict__ binCnt) {
    __shared__ int l[NB];
    int t = threadIdx.x;
    int f64 = flags[0];
    for (int i = t; i < NB; i += 256) l[i] = 0;
    __syncthreads();
    int base = blockIdx.x * CH;
#pragma unroll
    for (int k = 0; k < CH / 256; k++) {
        int e = base + k * 256 + t;
        if (e < NEDGES) atomicAdd(&l[ldIdx(ei, f64, NEDGES + e) >> 9], 1);
    }
    __syncthreads();
    for (int i = t; i < NB; i += 256)
        if (l[i]) atomicAdd(&binCnt[i], l[i]);
}

__global__ __launch_bounds__(256) void k_binscan(const int* __restrict__ binCnt,
                                                 int* __restrict__ binOfs,
                                                 int* __restrict__ binCur) {
    __shared__ int sh[256];
    int t = threadIdx.x;
    int v = (t < NB) ? binCnt[t] : 0;
    sh[t] = v;
    __syncthreads();
    for (int off = 1; off < 256; off <<= 1) {
        int x = (t >= off) ? sh[t - off] : 0;
        __syncthreads();
        sh[t] += x;
        __syncthreads();
    }
    if (t < NB) {
        binOfs[t + 1] = sh[t];
        binCur[t] = sh[t] - v;      // exclusive
    }
    if (t == 0) binOfs[0] = 0;
}

__global__ __launch_bounds__(256) void k_binscatter(const void* __restrict__ ei,
                                                    const int* __restrict__ flags,
                                                    int* __restrict__ binCur,
                                                    int2* __restrict__ ebin) {
    __shared__ int lcnt[NB], lbase[NB], lofs[NB];
    int t = threadIdx.x;
    int f64 = flags[0];
    for (int i = t; i < NB; i += 256) lcnt[i] = 0;
    __syncthreads();
    int base = blockIdx.x * CH;
    int2 ed[CH / 256];
    int bn[CH / 256];
#pragma unroll
    for (int k = 0; k < CH / 256; k++) {
        int e = base + k * 256 + t;
        if (e < NEDGES) {
            ed[k].x = ldIdx(ei, f64, e);
            ed[k].y = ldIdx(ei, f64, NEDGES + e);
            bn[k] = ed[k].y >> 9;
            atomicAdd(&lcnt[bn[k]], 1);
        } else bn[k] = -1;
    }
    __syncthreads();
    if (t < NB) {
        int c = lcnt[t];
        lbase[t] = c ? atomicAdd(&binCur[t], c) : 0;
        lofs[t] = 0;
    }
    __syncthreads();
#pragma unroll
    for (int k = 0; k < CH / 256; k++) {
        if (bn[k] >= 0) {
            int p = lbase[bn[k]] + atomicAdd(&lofs[bn[k]], 1);
            ebin[p] = ed[k];
        }
    }
}

__global__ __launch_bounds__(256) void k_binfill(const int2* __restrict__ ebin,
                                                 const int* __restrict__ binOfs,
                                                 int* __restrict__ rowptr,
                                                 int* __restrict__ perm) {
    __shared__ int deg[512], lptr[512], ssum[256];
    int b = blockIdx.x, t = threadIdx.x;
    int n0 = b << 9;
    int nn = NNODES - n0; if (nn > 512) nn = 512;
    int e0 = binOfs[b], e1 = binOfs[b + 1];
    deg[t] = 0; deg[t + 256] = 0;
    __syncthreads();
    for (int e = e0 + t; e < e1; e += 256)
        atomicAdd(&deg[ebin[e].y - n0], 1);
    __syncthreads();
    int d0 = deg[2 * t], d1 = deg[2 * t + 1];
    int s = d0 + d1;
    ssum[t] = s;
    __syncthreads();
    for (int off = 1; off < 256; off <<= 1) {
        int x = (t >= off) ? ssum[t - off] : 0;
        __syncthreads();
        ssum[t] += x;
        __syncthreads();
    }
    int ex = ssum[t] - s;
    lptr[2 * t] = ex;
    lptr[2 * t + 1] = ex + d0;
    if (2 * t < nn)     rowptr[n0 + 2 * t] = e0 + ex;
    if (2 * t + 1 < nn) rowptr[n0 + 2 * t + 1] = e0 + ex + d0;
    if (b == NB - 1 && t == 0) rowptr[NNODES] = e1;
    deg[2 * t] = 0; deg[2 * t + 1] = 0;   // reuse as cursor
    __syncthreads();
    for (int e = e0 + t; e < e1; e += 256) {
        int2 ed = ebin[e];
        int d = ed.y - n0;
        int pos = e0 + lptr[d] + atomicAdd(&deg[d], 1);
        perm[pos] = ed.x;
    }
}

// ================= gather aggregation =================
// One node per wave; 4 groups of 16 lanes; lane (g,c) loads dwordx4 of one
// source row (16 lanes cover 256B). SINGLE dependent chain for deg<=24
// (97.8% of Poisson-16 rows): all 6 perm loads -> all 6 feat loads ->
// predicated accumulate. 16-edge chunks peeled only while >24 edges remain.
__device__ __forceinline__ void acc8(float* acc, uint4 u) {
    acc[0] += bfLo(u.x); acc[1] += bfHi(u.x);
    acc[2] += bfLo(u.y); acc[3] += bfHi(u.y);
    acc[4] += bfLo(u.z); acc[5] += bfHi(u.z);
    acc[6] += bfLo(u.w); acc[7] += bfHi(u.w);
}

__global__ __launch_bounds__(256) void k_gather(const unsigned short* __restrict__ feat,
                                                const unsigned short* __restrict__ x,
                                                const int* __restrict__ rowptr,
                                                const int* __restrict__ perm,
                                                unsigned short* __restrict__ out) {
    int wave = threadIdx.x >> 6, lane = threadIdx.x & 63;
    int i = blockIdx.x * 4 + wave;        // NNODES = 25000*4 exactly
    int g = lane >> 4, c = lane & 15;
    const uint4* F = (const uint4*)feat;  // one row = 16 uint4

    // independent head loads first: x row + rowptr (overlap whole chain)
    uint4 xv = ((const uint4*)x)[i * 16 + c];
    int jb = rowptr[i], je = rowptr[i + 1];

    float acc[8];
#pragma unroll
    for (int k = 0; k < 8; k++) acc[k] = 0.f;

    int j = jb;
    // rare slow path (deg > 24, ~2.2%): peel 16-edge chunks
    while (je - j > 24) {
        int s0 = perm[j + g], s1 = perm[j + 4 + g];
        int s2 = perm[j + 8 + g], s3 = perm[j + 12 + g];
        uint4 u0 = F[s0 * 16 + c];
        uint4 u1 = F[s1 * 16 + c];
        uint4 u2 = F[s2 * 16 + c];
        uint4 u3 = F[s3 * 16 + c];
        acc8(acc, u0); acc8(acc, u1); acc8(acc, u2); acc8(acc, u3);
        j += 16;
    }
    // single-chain fast path: remaining 1..24 edges in one shot (6 slots x 4 groups)
    if (j < je) {
        int pm[6];
#pragma unroll
        for (int k = 0; k < 6; k++) {
            int e = j + 4 * k + g;
            pm[k] = perm[e < je ? e : (je - 1)];
        }
        uint4 u[6];
#pragma unroll
        for (int k = 0; k < 6; k++) u[k] = F[pm[k] * 16 + c];
#pragma unroll
        for (int k = 0; k < 6; k++)
            if (j + 4 * k + g < je) acc8(acc, u[k]);
    }

    // combine the 4 group partials (feature layout identical across groups)
#pragma unroll
    for (int k = 0; k < 8; k++) {
        acc[k] += __shfl_xor(acc[k], 16);
        acc[k] += __shfl_xor(acc[k], 32);
    }

    // h = x + agg
    acc[0] += bfLo(xv.x); acc[1] += bfHi(xv.x);
    acc[2] += bfLo(xv.y); acc[3] += bfHi(xv.y);
    acc[4] += bfLo(xv.z); acc[5] += bfHi(xv.z);
    acc[6] += bfLo(xv.w); acc[7] += bfHi(xv.w);

    if (g == 0) {
        uint4 r;
        r.x = ((unsigned int)f2bf(acc[1]) << 16) | f2bf(acc[0]);
        r.y = ((unsigned int)f2bf(acc[3]) << 16) | f2bf(acc[2]);
        r.z = ((unsigned int)f2bf(acc[5]) << 16) | f2bf(acc[4]);
        r.w = ((unsigned int)f2bf(acc[7]) << 16) | f2bf(acc[6]);
        ((uint4*)out)[i * 16 + c] = r;
    }
}

// ---------------- persistent register-resident-B GEMM: C = relu(A@W + bias).
// 2048 waves grid-stride 6250 row-tiles (~3 each). W (128 VGPR) + bias loaded
// ONCE per wave; per tile: 4 A-loads (b128) + 32 MFMA + stores. Independent
// iterations let the compiler pipeline next-tile A-loads under MFMAs.
// Layouts (m89/m91): A[m=lane&15][k=quad*8+j]; B[k=quad*8+j][n=lane&15];
// D: col=lane&15, row=quad*4+reg.
__global__ __launch_bounds__(256, 2) void k_gemm_rb(const unsigned short* __restrict__ A,
                                                    const unsigned short* __restrict__ WT,
                                                    const float* __restrict__ bias,
                                                    unsigned short* __restrict__ out) {
    int gw = blockIdx.x * 4 + (threadIdx.x >> 6);   // global wave id
    int lane = threadIdx.x & 63;
    int m = lane & 15, quad = lane >> 4;

    bf16x8 bfr[8][4];
#pragma unroll
    for (int nt = 0; nt < 8; nt++) {
        const unsigned short* Bb = WT + (nt * 16 + m) * DF + quad * 8;
#pragma unroll
        for (int ks = 0; ks < 4; ks++)
            bfr[nt][ks] = *(const bf16x8*)(Bb + ks * 32);
    }
    float bv[8];
#pragma unroll
    for (int nt = 0; nt < 8; nt++) bv[nt] = bias[nt * 16 + m];

    for (int tile = gw; tile < NNODES / 16; tile += GEMM_WAVES) {
        int r0 = tile * 16;
        const unsigned short* Ab = A + (r0 + m) * DF + quad * 8;
        bf16x8 a[4];
#pragma unroll
        for (int ks = 0; ks < 4; ks++) a[ks] = *(const bf16x8*)(Ab + ks * 32);

        f32x4 acc[8];
#pragma unroll
        for (int nt = 0; nt < 8; nt++) acc[nt] = (f32x4){0.f, 0.f, 0.f, 0.f};
#pragma unroll
        for (int nt = 0; nt < 8; nt++)
#pragma unroll
            for (int ks = 0; ks < 4; ks++)
                acc[nt] = __builtin_amdgcn_mfma_f32_16x16x32_bf16(a[ks], bfr[nt][ks], acc[nt], 0, 0, 0);

#pragma unroll
        for (int nt = 0; nt < 8; nt++) {
            int col = nt * 16 + m;
#pragma unroll
            for (int reg = 0; reg < 4; reg++) {
                int row = r0 + quad * 4 + reg;
                float v = acc[nt][reg] + bv[nt];
                if (v < 0.f) v = 0.f;
                out[row * DF + col] = f2bf(v);
            }
        }
    }
}

// ---------------- persistent fc (128 -> 40, padded 48) + fused log_softmax.
__global__ __launch_bounds__(256, 2) void k_fc_rb(const unsigned short* __restrict__ A,
                                                  const unsigned short* __restrict__ WfcT,
                                                  const float* __restrict__ bfc,
                                                  const int* __restrict__ flags,
                                                  void* __restrict__ out) {
    int gw = blockIdx.x * 4 + (threadIdx.x >> 6);
    int lane = threadIdx.x & 63;
    int m = lane & 15, quad = lane >> 4;
    bool valid2 = (m < 8);
    int obf = flags[1];

    bf16x8 bfr[3][4];
#pragma unroll
    for (int nt = 0; nt < 3; nt++) {
        const unsigned short* Bb = WfcT + (nt * 16 + m) * DF + quad * 8;
#pragma unroll
        for (int ks = 0; ks < 4; ks++)
            bfr[nt][ks] = *(const bf16x8*)(Bb + ks * 32);
    }
    float bv0 = bfc[m], bv1 = bfc[16 + m];
    float bv2 = valid2 ? bfc[32 + m] : 0.f;

    for (int tile = gw; tile < NNODES / 16; tile += GEMM_WAVES) {
        int r0 = tile * 16;
        const unsigned short* Ab = A + (r0 + m) * DF + quad * 8;
        bf16x8 a[4];
#pragma unroll
        for (int ks = 0; ks < 4; ks++) a[ks] = *(const bf16x8*)(Ab + ks * 32);

        f32x4 acc[3];
#pragma unroll
        for (int nt = 0; nt < 3; nt++) acc[nt] = (f32x4){0.f, 0.f, 0.f, 0.f};
#pragma unroll
        for (int nt = 0; nt < 3; nt++)
#pragma unroll
            for (int ks = 0; ks < 4; ks++)
                acc[nt] = __builtin_amdgcn_mfma_f32_16x16x32_bf16(a[ks], bfr[nt][ks], acc[nt], 0, 0, 0);

#pragma unroll
        for (int reg = 0; reg < 4; reg++) {
            float v0 = acc[0][reg] + bv0;
            float v1 = acc[1][reg] + bv1;
            float v2 = valid2 ? (acc[2][reg] + bv2) : -3.0e38f;
            float mx = fmaxf(fmaxf(v0, v1), v2);
#pragma unroll
            for (int off = 1; off < 16; off <<= 1) mx = fmaxf(mx, __shfl_xor(mx, off, 16));
            float e = __expf(v0 - mx) + __expf(v1 - mx) + (valid2 ? __expf(v2 - mx) : 0.f);
#pragma unroll
            for (int off = 1; off < 16; off <<= 1) e += __shfl_xor(e, off, 16);
            float l = mx + __logf(e);
            int row = r0 + quad * 4 + reg;
            if (obf) {
                unsigned short* o = (unsigned short*)out + row * NC;
                o[m] = f2bf(v0 - l);
                o[16 + m] = f2bf(v1 - l);
                if (valid2) o[32 + m] = f2bf(v2 - l);
            } else {
                float* o = (float*)out + row * NC;
                o[m] = v0 - l;
                o[16 + m] = v1 - l;
                if (valid2) o[32 + m] = v2 - l;
            }
        }
    }
}

extern "C" void kernel_launch(void* const* d_in, const int* in_sizes, int n_in,
                              void* d_out, int out_size, void* d_ws, size_t ws_size,
                              hipStream_t stream) {
    const void* x   = d_in[0];
    const void* ei  = d_in[1];
    const void* w1a = d_in[2];
    const void* b1a = d_in[3];
    const void* w1b = d_in[4];
    const void* b1b = d_in[5];
    const void* w2a = d_in[6];
    const void* b2a = d_in[7];
    const void* w2b = d_in[8];
    const void* b2b = d_in[9];
    const void* wfc = d_in[10];
    const void* bfc = d_in[11];

    char* ws = (char*)d_ws;
    size_t off = 0;
    auto alloc = [&](size_t bytes) {
        void* p = ws + off;
        off += (bytes + 255) & ~(size_t)255;
        return p;
    };
    unsigned short* B0    = (unsigned short*)alloc((size_t)NNODES * DF * 2);
    unsigned short* B1    = (unsigned short*)alloc((size_t)NNODES * DF * 2);
    unsigned short* B2    = (unsigned short*)alloc((size_t)NNODES * DF * 2);
    int2*           ebin  = (int2*)alloc((size_t)NEDGES * 8);
    int*            perm  = (int*)alloc((size_t)NEDGES * 4);
    int*            rowptr= (int*)alloc((size_t)(NNODES + 1) * 4);
    int*            binCnt= (int*)alloc(NB * 4);
    int*            binOfs= (int*)alloc((NB + 1) * 4);
    int*            binCur= (int*)alloc(NB * 4);
    int*            flags = (int*)alloc(256);
    unsigned short* wAll  = (unsigned short*)alloc((4 * 16384 + NCP * 128) * 2);
    float*          bAll  = (float*)alloc((512 + NC) * 4);

    unsigned short* w1aT = wAll;
    unsigned short* w1bT = wAll + 16384;
    unsigned short* w2aT = wAll + 32768;
    unsigned short* w2bT = wAll + 49152;
    unsigned short* wfcT = wAll + 65536;
    float* b1af = bAll;
    float* b1bf = bAll + 128;
    float* b2af = bAll + 256;
    float* b2bf = bAll + 384;
    float* bfcf = bAll + 512;

    // ---- dtype detection + canonicalization
    k_detect<<<1, 256, 0, stream>>>((const unsigned int*)ei, (const unsigned int*)x, flags);
    k_cvt_feat<<<(NNODES * DF + 255) / 256, 256, 0, stream>>>(x, flags, B0, NNODES * DF);

    int wprepN = 4 * 16384 + NCP * 128 + 512 + NC;
    k_wprep<<<(wprepN + 255) / 256, 256, 0, stream>>>(w1a, w1b, w2a, w2b, wfc,
                                                      b1a, b1b, b2a, b2b, bfc,
                                                      flags, wAll, bAll);

    // ---- binned CSR build (reads edge_index directly)
    hipMemsetAsync(binCnt, 0, NB * 4, stream);
    int nEB = (NEDGES + CH - 1) / CH;                          // 391
    k_bincount<<<nEB, 256, 0, stream>>>(ei, flags, binCnt);
    k_binscan<<<1, 256, 0, stream>>>(binCnt, binOfs, binCur);
    k_binscatter<<<nEB, 256, 0, stream>>>(ei, flags, binCur, ebin);
    k_binfill<<<NB, 256, 0, stream>>>(ebin, binOfs, rowptr, perm);

    const int gatherGrid = NNODES / 4;                         // 25000

    // ---- layer 1
    k_gather<<<gatherGrid, 256, 0, stream>>>(B0, B0, rowptr, perm, B1);
    k_gemm_rb<<<GEMM_BLOCKS, 256, 0, stream>>>(B1, w1aT, b1af, B2);
    k_gemm_rb<<<GEMM_BLOCKS, 256, 0, stream>>>(B2, w1bT, b1bf, B1);   // h1 -> B1

    // ---- layer 2
    k_gather<<<gatherGrid, 256, 0, stream>>>(B1, B1, rowptr, perm, B2);
    k_gemm_rb<<<GEMM_BLOCKS, 256, 0, stream>>>(B2, w2aT, b2af, B0);
    k_gemm_rb<<<GEMM_BLOCKS, 256, 0, stream>>>(B0, w2bT, b2bf, B2);   // h2 -> B2

    // ---- fc + log_softmax
    k_fc_rb<<<GEMM_BLOCKS, 256, 0, stream>>>(B2, wfcT, bfcf, flags, d_out);
}

// Round 4
// 375.791 us; speedup vs baseline: 1.1125x; 1.0510x over previous
//
#include <hip/hip_runtime.h>
#include <hip/hip_bf16.h>

#define NNODES 100000
#define NEDGES 1600000
#define DF 128
#define NC 40
#define NCP 48          // padded fc cols (3 x 16)
#define NB 196          // CSR bins: dst>>9, 512 nodes/bin
#define CH 4096         // edges per binscatter/bincount block
#define GEMM_BLOCKS 512 // persistent: 2 blocks/CU x 256 CU
#define GEMM_WAVES (GEMM_BLOCKS * 4)
#define ZROW NNODES     // zero feature row appended to B0/B1

typedef __bf16 bf16x8 __attribute__((ext_vector_type(8)));
typedef float f32x4 __attribute__((ext_vector_type(4)));
typedef float f32x2 __attribute__((ext_vector_type(2)));

__device__ __forceinline__ unsigned short f2bf(float f) {
    unsigned int u = __builtin_bit_cast(unsigned int, f);
    u = (u + 0x7FFFu + ((u >> 16) & 1u)) >> 16;   // RNE
    return (unsigned short)u;
}
__device__ __forceinline__ float bf2f(unsigned short s) {
    unsigned int u = ((unsigned int)s) << 16;
    return __builtin_bit_cast(float, u);
}
__device__ __forceinline__ float bfLo(unsigned int u) {
    return __builtin_bit_cast(float, u << 16);
}
__device__ __forceinline__ float bfHi(unsigned int u) {
    return __builtin_bit_cast(float, u & 0xFFFF0000u);
}
__device__ __forceinline__ f32x2 up2(unsigned int u) {
    return (f32x2){bfLo(u), bfHi(u)};
}

// ---------------- dtype detection (flags[0]: ei is int64; flags[1]: floats are bf16)
// also zeroes binCnt (fused memset).
__global__ void k_detect(const unsigned int* __restrict__ ei32,
                         const unsigned int* __restrict__ x32,
                         int* __restrict__ flags,
                         int* __restrict__ binCnt) {
    __shared__ unsigned int rOr[256];
    __shared__ int rCnt[256];
    for (int i = threadIdx.x; i < NB; i += 256) binCnt[i] = 0;
    unsigned int o = 0; int c = 0;
    for (int i = threadIdx.x; i < 1024; i += 256) o |= ei32[2 * i + 1];
    for (int i = threadIdx.x; i < 4096; i += 256) {
        unsigned int e = (x32[i] >> 7) & 0xFFu;
        c += (e >= 100u && e <= 140u) ? 1 : 0;
    }
    rOr[threadIdx.x] = o; rCnt[threadIdx.x] = c;
    __syncthreads();
    for (int s = 128; s; s >>= 1) {
        if ((int)threadIdx.x < s) {
            rOr[threadIdx.x] |= rOr[threadIdx.x + s];
            rCnt[threadIdx.x] += rCnt[threadIdx.x + s];
        }
        __syncthreads();
    }
    if (threadIdx.x == 0) {
        flags[0] = (rOr[0] == 0u) ? 1 : 0;
        flags[1] = (rCnt[0] > 2457) ? 1 : 0;
    }
}

__device__ __forceinline__ int ldIdx(const void* ei, int flag64, int i) {
    return flag64 ? (int)((const long long*)ei)[i] : ((const int*)ei)[i];
}

// ---------------- features -> canonical bf16, 8 elems/thread (vectorized)
__global__ __launch_bounds__(256) void k_cvt_feat(const void* __restrict__ src,
                                                  const int* __restrict__ flags,
                                                  unsigned short* __restrict__ dst) {
    int i = blockIdx.x * 256 + threadIdx.x;   // 6250 blocks: i < 1.6M, 8 elems each
    if (flags[1]) {
        ((uint4*)dst)[i] = ((const uint4*)src)[i];
    } else {
        uint4 a = ((const uint4*)src)[2 * i];
        uint4 b = ((const uint4*)src)[2 * i + 1];
        auto pk = [](unsigned int lo, unsigned int hi) -> unsigned int {
            return ((unsigned int)f2bf(__builtin_bit_cast(float, hi)) << 16) |
                   f2bf(__builtin_bit_cast(float, lo));
        };
        uint4 r;
        r.x = pk(a.x, a.y);
        r.y = pk(a.z, a.w);
        r.z = pk(b.x, b.y);
        r.w = pk(b.z, b.w);
        ((uint4*)dst)[i] = r;
    }
}

// ---------------- all weights (transposed bf16) + biases (fp32) + zero-row pads.
__global__ __launch_bounds__(256) void k_wprep(const void* w1a, const void* w1b,
                                               const void* w2a, const void* w2b,
                                               const void* wfc,
                                               const void* b1a, const void* b1b,
                                               const void* b2a, const void* b2b,
                                               const void* bfc,
                                               const int* __restrict__ flags,
                                               unsigned short* __restrict__ wAll,
                                               float* __restrict__ bAll,
                                               unsigned short* __restrict__ pad0,
                                               unsigned short* __restrict__ pad1) {
    int idx = blockIdx.x * 256 + threadIdx.x;
    int bf = flags[1];
    auto ldf = [&](const void* p, int i) -> float {
        return bf ? bf2f(((const unsigned short*)p)[i]) : ((const float*)p)[i];
    };
    if (idx < 65536) {                       // 4 square transposes
        int wi = idx >> 14, r = idx & 16383;
        int n = r >> 7, k = r & 127;
        const void* s = (wi == 0) ? w1a : (wi == 1) ? w1b : (wi == 2) ? w2a : w2b;
        wAll[idx] = f2bf(ldf(s, k * 128 + n));
    } else if (idx < 65536 + NCP * 128) {    // wfc transpose, zero pad
        int r = idx - 65536;
        int n = r >> 7, k = r & 127;
        wAll[idx] = (n < NC) ? f2bf(ldf(wfc, k * NC + n)) : (unsigned short)0;
    } else if (idx < 65536 + NCP * 128 + 512 + NC) {
        int r = idx - (65536 + NCP * 128);
        const void* s; int i;
        if (r < 128)      { s = b1a; i = r; }
        else if (r < 256) { s = b1b; i = r - 128; }
        else if (r < 384) { s = b2a; i = r - 256; }
        else if (r < 512) { s = b2b; i = r - 384; }
        else              { s = bfc; i = r - 512; }
        bAll[r] = ldf(s, i);
    } else if (idx < 65536 + NCP * 128 + 512 + NC + 256) {
        pad0[idx - (65536 + NCP * 128 + 512 + NC)] = 0;   // B0 zero row
    } else if (idx < 65536 + NCP * 128 + 512 + NC + 512) {
        pad1[idx - (65536 + NCP * 128 + 512 + NC + 256)] = 0;  // B1 zero row
    }
}

// ================= binned CSR build =================
__global__ __launch_bounds__(256) void k_bincount(const void* __restrict__ ei,
                                                  const int* __restrict__ flags,
                                                  int* __restrict__ binCnt) {
    __shared__ int l[NB];
    int t = threadIdx.x;
    int f64 = flags[0];
    for (int i = t; i < NB; i += 256) l[i] = 0;
    __syncthreads();
    int base = blockIdx.x * CH;
#pragma unroll
    for (int k = 0; k < CH / 256; k++) {
        int e = base + k * 256 + t;
        if (e < NEDGES) atomicAdd(&l[ldIdx(ei, f64, NEDGES + e) >> 9], 1);
    }
    __syncthreads();
    for (int i = t; i < NB; i += 256)
        if (l[i]) atomicAdd(&binCnt[i], l[i]);
}

__global__ __launch_bounds__(256) void k_binscan(const int* __restrict__ binCnt,
                                                 int* __restrict__ binOfs,
                                                 int* __restrict__ binCur) {
    __shared__ int sh[256];
    int t = threadIdx.x;
    int v = (t < NB) ? binCnt[t] : 0;
    sh[t] = v;
    __syncthreads();
    for (int off = 1; off < 256; off <<= 1) {
        int x = (t >= off) ? sh[t - off] : 0;
        __syncthreads();
        sh[t] += x;
        __syncthreads();
    }
    if (t < NB) {
        binOfs[t + 1] = sh[t];
        binCur[t] = sh[t] - v;      // exclusive
    }
    if (t == 0) binOfs[0] = 0;
}

__global__ __launch_bounds__(256) void k_binscatter(const void* __restrict__ ei,
                                                    const int* __restrict__ flags,
                                                    int* __restrict__ binCur,
                                                    int2* __restrict__ ebin) {
    __shared__ int lcnt[NB], lbase[NB], lofs[NB];
    int t = threadIdx.x;
    int f64 = flags[0];
    for (int i = t; i < NB; i += 256) lcnt[i] = 0;
    __syncthreads();
    int base = blockIdx.x * CH;
    int2 ed[CH / 256];
    int bn[CH / 256];
#pragma unroll
    for (int k = 0; k < CH / 256; k++) {
        int e = base + k * 256 + t;
        if (e < NEDGES) {
            ed[k].x = ldIdx(ei, f64, e);
            ed[k].y = ldIdx(ei, f64, NEDGES + e);
            bn[k] = ed[k].y >> 9;
            atomicAdd(&lcnt[bn[k]], 1);
        } else bn[k] = -1;
    }
    __syncthreads();
    if (t < NB) {
        int c = lcnt[t];
        lbase[t] = c ? atomicAdd(&binCur[t], c) : 0;
        lofs[t] = 0;
    }
    __syncthreads();
#pragma unroll
    for (int k = 0; k < CH / 256; k++) {
        if (bn[k] >= 0) {
            int p = lbase[bn[k]] + atomicAdd(&lofs[bn[k]], 1);
            ebin[p] = ed[k];
        }
    }
}

__global__ __launch_bounds__(256) void k_binfill(const int2* __restrict__ ebin,
                                                 const int* __restrict__ binOfs,
                                                 int* __restrict__ rowptr,
                                                 int* __restrict__ perm) {
    __shared__ int deg[512], lptr[512], ssum[256];
    int b = blockIdx.x, t = threadIdx.x;
    int n0 = b << 9;
    int nn = NNODES - n0; if (nn > 512) nn = 512;
    int e0 = binOfs[b], e1 = binOfs[b + 1];
    deg[t] = 0; deg[t + 256] = 0;
    __syncthreads();
    for (int e = e0 + t; e < e1; e += 256)
        atomicAdd(&deg[ebin[e].y - n0], 1);
    __syncthreads();
    int d0 = deg[2 * t], d1 = deg[2 * t + 1];
    int s = d0 + d1;
    ssum[t] = s;
    __syncthreads();
    for (int off = 1; off < 256; off <<= 1) {
        int x = (t >= off) ? ssum[t - off] : 0;
        __syncthreads();
        ssum[t] += x;
        __syncthreads();
    }
    int ex = ssum[t] - s;
    lptr[2 * t] = ex;
    lptr[2 * t + 1] = ex + d0;
    if (2 * t < nn)     rowptr[n0 + 2 * t] = e0 + ex;
    if (2 * t + 1 < nn) rowptr[n0 + 2 * t + 1] = e0 + ex + d0;
    if (b == NB - 1 && t == 0) rowptr[NNODES] = e1;
    deg[2 * t] = 0; deg[2 * t + 1] = 0;   // reuse as cursor
    __syncthreads();
    for (int e = e0 + t; e < e1; e += 256) {
        int2 ed = ebin[e];
        int d = ed.y - n0;
        int pos = e0 + lptr[d] + atomicAdd(&deg[d], 1);
        perm[pos] = ed.x;
    }
}

// ================= gather aggregation =================
// One node per wave; 4 groups of 16 lanes; lane (g,c) loads dwordx4 of one
// source row. Degree-bucketed straight-line paths (2/4/6 slots, wave-uniform
// branch); out-of-range slots cndmask the loaded perm value to ZROW (zeroed
// feature row) -> accumulate is UNCONDITIONAL (no predication, no addr clamp).
// perm is padded +64 so slot addresses never fault. acc as f32x2 -> v_pk_add_f32.
__device__ __forceinline__ void accu(f32x2* acc, uint4 u) {
    acc[0] += up2(u.x);
    acc[1] += up2(u.y);
    acc[2] += up2(u.z);
    acc[3] += up2(u.w);
}

template <int S>
__device__ __forceinline__ void gslots(const int* __restrict__ perm, const uint4* __restrict__ F,
                                       int j, int je, int g, int c, f32x2* acc) {
    int pm[S];
#pragma unroll
    for (int k = 0; k < S; k++) pm[k] = perm[j + 4 * k + g];
#pragma unroll
    for (int k = 0; k < S; k++)
        if (j + 4 * k + g >= je) pm[k] = ZROW;       // value-clamp, off the addr-issue path
    uint4 u[S];
#pragma unroll
    for (int k = 0; k < S; k++) u[k] = F[pm[k] * 16 + c];
#pragma unroll
    for (int k = 0; k < S; k++) accu(acc, u[k]);
}

__global__ __launch_bounds__(256) void k_gather(const unsigned short* __restrict__ feat,
                                                const unsigned short* __restrict__ x,
                                                const int* __restrict__ rowptr,
                                                const int* __restrict__ perm,
                                                unsigned short* __restrict__ out) {
    int wave = threadIdx.x >> 6, lane = threadIdx.x & 63;
    int i = blockIdx.x * 4 + wave;        // NNODES = 25000*4 exactly
    int g = lane >> 4, c = lane & 15;
    const uint4* F = (const uint4*)feat;  // one row = 16 uint4

    // independent head loads first: x row + rowptr (overlap whole chain)
    uint4 xv = ((const uint4*)x)[i * 16 + c];
    int jb = rowptr[i], je = rowptr[i + 1];

    f32x2 acc[4];
#pragma unroll
    for (int k = 0; k < 4; k++) acc[k] = (f32x2){0.f, 0.f};

    int j = jb;
    // rare slow path (deg > 24, ~2.2%): peel 16-edge chunks (all-valid, unconditional)
    while (je - j > 24) {
        int s0 = perm[j + g], s1 = perm[j + 4 + g];
        int s2 = perm[j + 8 + g], s3 = perm[j + 12 + g];
        uint4 u0 = F[s0 * 16 + c];
        uint4 u1 = F[s1 * 16 + c];
        uint4 u2 = F[s2 * 16 + c];
        uint4 u3 = F[s3 * 16 + c];
        accu(acc, u0); accu(acc, u1); accu(acc, u2); accu(acc, u3);
        j += 16;
    }
    int deg = je - j;                     // 0..24, wave-uniform
    if (deg > 16)      gslots<6>(perm, F, j, je, g, c, acc);
    else if (deg > 8)  gslots<4>(perm, F, j, je, g, c, acc);
    else if (deg > 0)  gslots<2>(perm, F, j, je, g, c, acc);

    // combine the 4 group partials
#pragma unroll
    for (int k = 0; k < 4; k++) {
        acc[k][0] += __shfl_xor(acc[k][0], 16);
        acc[k][1] += __shfl_xor(acc[k][1], 16);
        acc[k][0] += __shfl_xor(acc[k][0], 32);
        acc[k][1] += __shfl_xor(acc[k][1], 32);
    }

    // h = x + agg
    acc[0] += up2(xv.x);
    acc[1] += up2(xv.y);
    acc[2] += up2(xv.z);
    acc[3] += up2(xv.w);

    if (g == 0) {
        uint4 r;
        r.x = ((unsigned int)f2bf(acc[0][1]) << 16) | f2bf(acc[0][0]);
        r.y = ((unsigned int)f2bf(acc[1][1]) << 16) | f2bf(acc[1][0]);
        r.z = ((unsigned int)f2bf(acc[2][1]) << 16) | f2bf(acc[2][0]);
        r.w = ((unsigned int)f2bf(acc[3][1]) << 16) | f2bf(acc[3][0]);
        ((uint4*)out)[i * 16 + c] = r;
    }
}

// ---------------- persistent register-resident-B GEMM: C = relu(A@W + bias).
__global__ __launch_bounds__(256, 2) void k_gemm_rb(const unsigned short* __restrict__ A,
                                                    const unsigned short* __restrict__ WT,
                                                    const float* __restrict__ bias,
                                                    unsigned short* __restrict__ out) {
    int gw = blockIdx.x * 4 + (threadIdx.x >> 6);   // global wave id
    int lane = threadIdx.x & 63;
    int m = lane & 15, quad = lane >> 4;

    bf16x8 bfr[8][4];
#pragma unroll
    for (int nt = 0; nt < 8; nt++) {
        const unsigned short* Bb = WT + (nt * 16 + m) * DF + quad * 8;
#pragma unroll
        for (int ks = 0; ks < 4; ks++)
            bfr[nt][ks] = *(const bf16x8*)(Bb + ks * 32);
    }
    float bv[8];
#pragma unroll
    for (int nt = 0; nt < 8; nt++) bv[nt] = bias[nt * 16 + m];

    for (int tile = gw; tile < NNODES / 16; tile += GEMM_WAVES) {
        int r0 = tile * 16;
        const unsigned short* Ab = A + (r0 + m) * DF + quad * 8;
        bf16x8 a[4];
#pragma unroll
        for (int ks = 0; ks < 4; ks++) a[ks] = *(const bf16x8*)(Ab + ks * 32);

        f32x4 acc[8];
#pragma unroll
        for (int nt = 0; nt < 8; nt++) acc[nt] = (f32x4){0.f, 0.f, 0.f, 0.f};
#pragma unroll
        for (int nt = 0; nt < 8; nt++)
#pragma unroll
            for (int ks = 0; ks < 4; ks++)
                acc[nt] = __builtin_amdgcn_mfma_f32_16x16x32_bf16(a[ks], bfr[nt][ks], acc[nt], 0, 0, 0);

#pragma unroll
        for (int nt = 0; nt < 8; nt++) {
            int col = nt * 16 + m;
#pragma unroll
            for (int reg = 0; reg < 4; reg++) {
                int row = r0 + quad * 4 + reg;
                float v = acc[nt][reg] + bv[nt];
                if (v < 0.f) v = 0.f;
                out[row * DF + col] = f2bf(v);
            }
        }
    }
}

// ---------------- persistent fc (128 -> 40, padded 48) + fused log_softmax.
__global__ __launch_bounds__(256, 2) void k_fc_rb(const unsigned short* __restrict__ A,
                                                  const unsigned short* __restrict__ WfcT,
                                                  const float* __restrict__ bfc,
                                                  const int* __restrict__ flags,
                                                  void* __restrict__ out) {
    int gw = blockIdx.x * 4 + (threadIdx.x >> 6);
    int lane = threadIdx.x & 63;
    int m = lane & 15, quad = lane >> 4;
    bool valid2 = (m < 8);
    int obf = flags[1];

    bf16x8 bfr[3][4];
#pragma unroll
    for (int nt = 0; nt < 3; nt++) {
        const unsigned short* Bb = WfcT + (nt * 16 + m) * DF + quad * 8;
#pragma unroll
        for (int ks = 0; ks < 4; ks++)
            bfr[nt][ks] = *(const bf16x8*)(Bb + ks * 32);
    }
    float bv0 = bfc[m], bv1 = bfc[16 + m];
    float bv2 = valid2 ? bfc[32 + m] : 0.f;

    for (int tile = gw; tile < NNODES / 16; tile += GEMM_WAVES) {
        int r0 = tile * 16;
        const unsigned short* Ab = A + (r0 + m) * DF + quad * 8;
        bf16x8 a[4];
#pragma unroll
        for (int ks = 0; ks < 4; ks++) a[ks] = *(const bf16x8*)(Ab + ks * 32);

        f32x4 acc[3];
#pragma unroll
        for (int nt = 0; nt < 3; nt++) acc[nt] = (f32x4){0.f, 0.f, 0.f, 0.f};
#pragma unroll
        for (int nt = 0; nt < 3; nt++)
#pragma unroll
            for (int ks = 0; ks < 4; ks++)
                acc[nt] = __builtin_amdgcn_mfma_f32_16x16x32_bf16(a[ks], bfr[nt][ks], acc[nt], 0, 0, 0);

#pragma unroll
        for (int reg = 0; reg < 4; reg++) {
            float v0 = acc[0][reg] + bv0;
            float v1 = acc[1][reg] + bv1;
            float v2 = valid2 ? (acc[2][reg] + bv2) : -3.0e38f;
            float mx = fmaxf(fmaxf(v0, v1), v2);
#pragma unroll
            for (int off = 1; off < 16; off <<= 1) mx = fmaxf(mx, __shfl_xor(mx, off, 16));
            float e = __expf(v0 - mx) + __expf(v1 - mx) + (valid2 ? __expf(v2 - mx) : 0.f);
#pragma unroll
            for (int off = 1; off < 16; off <<= 1) e += __shfl_xor(e, off, 16);
            float l = mx + __logf(e);
            int row = r0 + quad * 4 + reg;
            if (obf) {
                unsigned short* o = (unsigned short*)out + row * NC;
                o[m] = f2bf(v0 - l);
                o[16 + m] = f2bf(v1 - l);
                if (valid2) o[32 + m] = f2bf(v2 - l);
            } else {
                float* o = (float*)out + row * NC;
                o[m] = v0 - l;
                o[16 + m] = v1 - l;
                if (valid2) o[32 + m] = v2 - l;
            }
        }
    }
}

extern "C" void kernel_launch(void* const* d_in, const int* in_sizes, int n_in,
                              void* d_out, int out_size, void* d_ws, size_t ws_size,
                              hipStream_t stream) {
    const void* x   = d_in[0];
    const void* ei  = d_in[1];
    const void* w1a = d_in[2];
    const void* b1a = d_in[3];
    const void* w1b = d_in[4];
    const void* b1b = d_in[5];
    const void* w2a = d_in[6];
    const void* b2a = d_in[7];
    const void* w2b = d_in[8];
    const void* b2b = d_in[9];
    const void* wfc = d_in[10];
    const void* bfc = d_in[11];

    char* ws = (char*)d_ws;
    size_t off = 0;
    auto alloc = [&](size_t bytes) {
        void* p = ws + off;
        off += (bytes + 255) & ~(size_t)255;
        return p;
    };
    // B0/B1 have one extra zeroed row (ZROW) for the gather's slot clamp.
    unsigned short* B0    = (unsigned short*)alloc((size_t)(NNODES + 1) * DF * 2);
    unsigned short* B1    = (unsigned short*)alloc((size_t)(NNODES + 1) * DF * 2);
    unsigned short* B2    = (unsigned short*)alloc((size_t)NNODES * DF * 2);
    int2*           ebin  = (int2*)alloc((size_t)NEDGES * 8);
    int*            perm  = (int*)alloc((size_t)(NEDGES + 64) * 4);   // +64 pad: slot over-read
    int*            rowptr= (int*)alloc((size_t)(NNODES + 1) * 4);
    int*            binCnt= (int*)alloc(NB * 4);
    int*            binOfs= (int*)alloc((NB + 1) * 4);
    int*            binCur= (int*)alloc(NB * 4);
    int*            flags = (int*)alloc(256);
    unsigned short* wAll  = (unsigned short*)alloc((4 * 16384 + NCP * 128) * 2);
    float*          bAll  = (float*)alloc((512 + NC) * 4);

    unsigned short* w1aT = wAll;
    unsigned short* w1bT = wAll + 16384;
    unsigned short* w2aT = wAll + 32768;
    unsigned short* w2bT = wAll + 49152;
    unsigned short* wfcT = wAll + 65536;
    float* b1af = bAll;
    float* b1bf = bAll + 128;
    float* b2af = bAll + 256;
    float* b2bf = bAll + 384;
    float* bfcf = bAll + 512;

    // ---- dtype detection (+ binCnt zero) + canonicalization
    k_detect<<<1, 256, 0, stream>>>((const unsigned int*)ei, (const unsigned int*)x, flags, binCnt);
    k_cvt_feat<<<NNODES * DF / (256 * 8), 256, 0, stream>>>(x, flags, B0);   // 6250 blocks

    int wprepN = 4 * 16384 + NCP * 128 + 512 + NC + 512;
    k_wprep<<<(wprepN + 255) / 256, 256, 0, stream>>>(w1a, w1b, w2a, w2b, wfc,
                                                      b1a, b1b, b2a, b2b, bfc,
                                                      flags, wAll, bAll,
                                                      B0 + (size_t)NNODES * DF,
                                                      B1 + (size_t)NNODES * DF);

    // ---- binned CSR build (reads edge_index directly)
    int nEB = (NEDGES + CH - 1) / CH;                          // 391
    k_bincount<<<nEB, 256, 0, stream>>>(ei, flags, binCnt);
    k_binscan<<<1, 256, 0, stream>>>(binCnt, binOfs, binCur);
    k_binscatter<<<nEB, 256, 0, stream>>>(ei, flags, binCur, ebin);
    k_binfill<<<NB, 256, 0, stream>>>(ebin, binOfs, rowptr, perm);

    const int gatherGrid = NNODES / 4;                         // 25000

    // ---- layer 1
    k_gather<<<gatherGrid, 256, 0, stream>>>(B0, B0, rowptr, perm, B1);
    k_gemm_rb<<<GEMM_BLOCKS, 256, 0, stream>>>(B1, w1aT, b1af, B2);
    k_gemm_rb<<<GEMM_BLOCKS, 256, 0, stream>>>(B2, w1bT, b1bf, B1);   // h1 -> B1

    // ---- layer 2
    k_gather<<<gatherGrid, 256, 0, stream>>>(B1, B1, rowptr, perm, B2);
    k_gemm_rb<<<GEMM_BLOCKS, 256, 0, stream>>>(B2, w2aT, b2af, B0);
    k_gemm_rb<<<GEMM_BLOCKS, 256, 0, stream>>>(B0, w2bT, b2bf, B2);   // h2 -> B2

    // ---- fc + log_softmax
    k_fc_rb<<<GEMM_BLOCKS, 256, 0, stream>>>(B2, wfcT, bfcf, flags, d_out);
}

// Round 5
// 375.078 us; speedup vs baseline: 1.1147x; 1.0019x over previous
//
#include <hip/hip_runtime.h>
#include <hip/hip_bf16.h>

#define NNODES 100000
#define NEDGES 1600000
#define DF 128
#define NC 40
#define NCP 48          // padded fc cols (3 x 16)
#define NB 196          // CSR bins: dst>>9, 512 nodes/bin
#define CH 4096         // edges per binscatter/bincount block
#define GEMM_BLOCKS 512 // persistent: 2 blocks/CU x 256 CU
#define GEMM_WAVES (GEMM_BLOCKS * 4)
#define ZROW NNODES     // zero feature row appended to B0/B1

typedef __bf16 bf16x8 __attribute__((ext_vector_type(8)));
typedef float f32x4 __attribute__((ext_vector_type(4)));
typedef float f32x2 __attribute__((ext_vector_type(2)));

__device__ __forceinline__ unsigned short f2bf(float f) {
    unsigned int u = __builtin_bit_cast(unsigned int, f);
    u = (u + 0x7FFFu + ((u >> 16) & 1u)) >> 16;   // RNE
    return (unsigned short)u;
}
__device__ __forceinline__ float bf2f(unsigned short s) {
    unsigned int u = ((unsigned int)s) << 16;
    return __builtin_bit_cast(float, u);
}
__device__ __forceinline__ float bfLo(unsigned int u) {
    return __builtin_bit_cast(float, u << 16);
}
__device__ __forceinline__ float bfHi(unsigned int u) {
    return __builtin_bit_cast(float, u & 0xFFFF0000u);
}
__device__ __forceinline__ f32x2 up2(unsigned int u) {
    return (f32x2){bfLo(u), bfHi(u)};
}

// ---------------- dtype detection (flags[0]: ei is int64; flags[1]: floats are bf16)
// also zeroes binCnt (fused memset).
__global__ void k_detect(const unsigned int* __restrict__ ei32,
                         const unsigned int* __restrict__ x32,
                         int* __restrict__ flags,
                         int* __restrict__ binCnt) {
    __shared__ unsigned int rOr[256];
    __shared__ int rCnt[256];
    for (int i = threadIdx.x; i < NB; i += 256) binCnt[i] = 0;
    unsigned int o = 0; int c = 0;
    for (int i = threadIdx.x; i < 1024; i += 256) o |= ei32[2 * i + 1];
    for (int i = threadIdx.x; i < 4096; i += 256) {
        unsigned int e = (x32[i] >> 7) & 0xFFu;
        c += (e >= 100u && e <= 140u) ? 1 : 0;
    }
    rOr[threadIdx.x] = o; rCnt[threadIdx.x] = c;
    __syncthreads();
    for (int s = 128; s; s >>= 1) {
        if ((int)threadIdx.x < s) {
            rOr[threadIdx.x] |= rOr[threadIdx.x + s];
            rCnt[threadIdx.x] += rCnt[threadIdx.x + s];
        }
        __syncthreads();
    }
    if (threadIdx.x == 0) {
        flags[0] = (rOr[0] == 0u) ? 1 : 0;
        flags[1] = (rCnt[0] > 2457) ? 1 : 0;
    }
}

__device__ __forceinline__ int ldIdx(const void* ei, int flag64, int i) {
    return flag64 ? (int)((const long long*)ei)[i] : ((const int*)ei)[i];
}

// ---------------- features -> canonical bf16, 8 elems/thread (vectorized)
__global__ __launch_bounds__(256) void k_cvt_feat(const void* __restrict__ src,
                                                  const int* __restrict__ flags,
                                                  unsigned short* __restrict__ dst) {
    int i = blockIdx.x * 256 + threadIdx.x;   // 6250 blocks: i < 1.6M, 8 elems each
    if (flags[1]) {
        ((uint4*)dst)[i] = ((const uint4*)src)[i];
    } else {
        uint4 a = ((const uint4*)src)[2 * i];
        uint4 b = ((const uint4*)src)[2 * i + 1];
        auto pk = [](unsigned int lo, unsigned int hi) -> unsigned int {
            return ((unsigned int)f2bf(__builtin_bit_cast(float, hi)) << 16) |
                   f2bf(__builtin_bit_cast(float, lo));
        };
        uint4 r;
        r.x = pk(a.x, a.y);
        r.y = pk(a.z, a.w);
        r.z = pk(b.x, b.y);
        r.w = pk(b.z, b.w);
        ((uint4*)dst)[i] = r;
    }
}

// ---------------- all weights (transposed bf16) + biases (fp32) + zero-row pads.
__global__ __launch_bounds__(256) void k_wprep(const void* w1a, const void* w1b,
                                               const void* w2a, const void* w2b,
                                               const void* wfc,
                                               const void* b1a, const void* b1b,
                                               const void* b2a, const void* b2b,
                                               const void* bfc,
                                               const int* __restrict__ flags,
                                               unsigned short* __restrict__ wAll,
                                               float* __restrict__ bAll,
                                               unsigned short* __restrict__ pad0,
                                               unsigned short* __restrict__ pad1) {
    int idx = blockIdx.x * 256 + threadIdx.x;
    int bf = flags[1];
    auto ldf = [&](const void* p, int i) -> float {
        return bf ? bf2f(((const unsigned short*)p)[i]) : ((const float*)p)[i];
    };
    if (idx < 65536) {                       // 4 square transposes
        int wi = idx >> 14, r = idx & 16383;
        int n = r >> 7, k = r & 127;
        const void* s = (wi == 0) ? w1a : (wi == 1) ? w1b : (wi == 2) ? w2a : w2b;
        wAll[idx] = f2bf(ldf(s, k * 128 + n));
    } else if (idx < 65536 + NCP * 128) {    // wfc transpose, zero pad
        int r = idx - 65536;
        int n = r >> 7, k = r & 127;
        wAll[idx] = (n < NC) ? f2bf(ldf(wfc, k * NC + n)) : (unsigned short)0;
    } else if (idx < 65536 + NCP * 128 + 512 + NC) {
        int r = idx - (65536 + NCP * 128);
        const void* s; int i;
        if (r < 128)      { s = b1a; i = r; }
        else if (r < 256) { s = b1b; i = r - 128; }
        else if (r < 384) { s = b2a; i = r - 256; }
        else if (r < 512) { s = b2b; i = r - 384; }
        else              { s = bfc; i = r - 512; }
        bAll[r] = ldf(s, i);
    } else if (idx < 65536 + NCP * 128 + 512 + NC + 256) {
        pad0[idx - (65536 + NCP * 128 + 512 + NC)] = 0;   // B0 zero row
    } else if (idx < 65536 + NCP * 128 + 512 + NC + 512) {
        pad1[idx - (65536 + NCP * 128 + 512 + NC + 256)] = 0;  // B1 zero row
    }
}

// ================= binned CSR build =================
__global__ __launch_bounds__(256) void k_bincount(const void* __restrict__ ei,
                                                  const int* __restrict__ flags,
                                                  int* __restrict__ binCnt) {
    __shared__ int l[NB];
    int t = threadIdx.x;
    int f64 = flags[0];
    for (int i = t; i < NB; i += 256) l[i] = 0;
    __syncthreads();
    int base = blockIdx.x * CH;
#pragma unroll
    for (int k = 0; k < CH / 256; k++) {
        int e = base + k * 256 + t;
        if (e < NEDGES) atomicAdd(&l[ldIdx(ei, f64, NEDGES + e) >> 9], 1);
    }
    __syncthreads();
    for (int i = t; i < NB; i += 256)
        if (l[i]) atomicAdd(&binCnt[i], l[i]);
}

__global__ __launch_bounds__(256) void k_binscan(const int* __restrict__ binCnt,
                                                 int* __restrict__ binOfs,
                                                 int* __restrict__ binCur) {
    __shared__ int sh[256];
    int t = threadIdx.x;
    int v = (t < NB) ? binCnt[t] : 0;
    sh[t] = v;
    __syncthreads();
    for (int off = 1; off < 256; off <<= 1) {
        int x = (t >= off) ? sh[t - off] : 0;
        __syncthreads();
        sh[t] += x;
        __syncthreads();
    }
    if (t < NB) {
        binOfs[t + 1] = sh[t];
        binCur[t] = sh[t] - v;      // exclusive
    }
    if (t == 0) binOfs[0] = 0;
}

__global__ __launch_bounds__(256) void k_binscatter(const void* __restrict__ ei,
                                                    const int* __restrict__ flags,
                                                    int* __restrict__ binCur,
                                                    int2* __restrict__ ebin) {
    __shared__ int lcnt[NB], lbase[NB], lofs[NB];
    int t = threadIdx.x;
    int f64 = flags[0];
    for (int i = t; i < NB; i += 256) lcnt[i] = 0;
    __syncthreads();
    int base = blockIdx.x * CH;
    int2 ed[CH / 256];
    int bn[CH / 256];
#pragma unroll
    for (int k = 0; k < CH / 256; k++) {
        int e = base + k * 256 + t;
        if (e < NEDGES) {
            ed[k].x = ldIdx(ei, f64, e);
            ed[k].y = ldIdx(ei, f64, NEDGES + e);
            bn[k] = ed[k].y >> 9;
            atomicAdd(&lcnt[bn[k]], 1);
        } else bn[k] = -1;
    }
    __syncthreads();
    if (t < NB) {
        int c = lcnt[t];
        lbase[t] = c ? atomicAdd(&binCur[t], c) : 0;
        lofs[t] = 0;
    }
    __syncthreads();
#pragma unroll
    for (int k = 0; k < CH / 256; k++) {
        if (bn[k] >= 0) {
            int p = lbase[bn[k]] + atomicAdd(&lofs[bn[k]], 1);
            ebin[p] = ed[k];
        }
    }
}

__global__ __launch_bounds__(256) void k_binfill(const int2* __restrict__ ebin,
                                                 const int* __restrict__ binOfs,
                                                 int* __restrict__ rowptr,
                                                 int* __restrict__ perm) {
    __shared__ int deg[512], lptr[512], ssum[256];
    int b = blockIdx.x, t = threadIdx.x;
    int n0 = b << 9;
    int nn = NNODES - n0; if (nn > 512) nn = 512;
    int e0 = binOfs[b], e1 = binOfs[b + 1];
    deg[t] = 0; deg[t + 256] = 0;
    __syncthreads();
    for (int e = e0 + t; e < e1; e += 256)
        atomicAdd(&deg[ebin[e].y - n0], 1);
    __syncthreads();
    int d0 = deg[2 * t], d1 = deg[2 * t + 1];
    int s = d0 + d1;
    ssum[t] = s;
    __syncthreads();
    for (int off = 1; off < 256; off <<= 1) {
        int x = (t >= off) ? ssum[t - off] : 0;
        __syncthreads();
        ssum[t] += x;
        __syncthreads();
    }
    int ex = ssum[t] - s;
    lptr[2 * t] = ex;
    lptr[2 * t + 1] = ex + d0;
    if (2 * t < nn)     rowptr[n0 + 2 * t] = e0 + ex;
    if (2 * t + 1 < nn) rowptr[n0 + 2 * t + 1] = e0 + ex + d0;
    if (b == NB - 1 && t == 0) rowptr[NNODES] = e1;
    deg[2 * t] = 0; deg[2 * t + 1] = 0;   // reuse as cursor
    __syncthreads();
    for (int e = e0 + t; e < e1; e += 256) {
        int2 ed = ebin[e];
        int d = ed.y - n0;
        int pos = e0 + lptr[d] + atomicAdd(&deg[d], 1);
        perm[pos] = ed.x;
    }
}

// ================= gather aggregation =================
// TWO nodes per wave, fully interleaved chains: 12 perm dwords -> 12 feature
// dwordx4 (12KB in flight/wave) -> unconditional accumulate (invalid slots
// value-clamped to ZROW zero row). 12500 blocks (2x block lifetime, half the
// WG dispatch pressure of 1-node/wave). Flat 6-slot per node (no buckets --
// R4 showed instruction cuts don't pay; this isolates the concurrency lever).
__device__ __forceinline__ void accu(f32x2* acc, uint4 u) {
    acc[0] += up2(u.x);
    acc[1] += up2(u.y);
    acc[2] += up2(u.z);
    acc[3] += up2(u.w);
}

__global__ __launch_bounds__(256) void k_gather(const unsigned short* __restrict__ feat,
                                                const unsigned short* __restrict__ x,
                                                const int* __restrict__ rowptr,
                                                const int* __restrict__ perm,
                                                unsigned short* __restrict__ out) {
    int wave = threadIdx.x >> 6, lane = threadIdx.x & 63;
    int i0 = (blockIdx.x * 4 + wave) * 2;     // node pair (i0, i0+1); 12500 blocks
    int g = lane >> 4, c = lane & 15;
    const uint4* F = (const uint4*)feat;      // one row = 16 uint4

    // independent head loads: both x rows + rowptr triple
    uint4 xv0 = ((const uint4*)x)[i0 * 16 + c];
    uint4 xv1 = ((const uint4*)x)[(i0 + 1) * 16 + c];
    int jb0 = rowptr[i0], mid = rowptr[i0 + 1], je1 = rowptr[i0 + 2];

    f32x2 a0[4], a1[4];
#pragma unroll
    for (int k = 0; k < 4; k++) { a0[k] = (f32x2){0.f, 0.f}; a1[k] = (f32x2){0.f, 0.f}; }

    int j0 = jb0, je0 = mid, j1 = mid;
    // rare slow path (deg > 24, ~2.2% of nodes): peel 16-edge chunks
    while (je0 - j0 > 24) {
        int s0 = perm[j0 + g], s1 = perm[j0 + 4 + g];
        int s2 = perm[j0 + 8 + g], s3 = perm[j0 + 12 + g];
        uint4 u0 = F[s0 * 16 + c], u1 = F[s1 * 16 + c];
        uint4 u2 = F[s2 * 16 + c], u3 = F[s3 * 16 + c];
        accu(a0, u0); accu(a0, u1); accu(a0, u2); accu(a0, u3);
        j0 += 16;
    }
    while (je1 - j1 > 24) {
        int s0 = perm[j1 + g], s1 = perm[j1 + 4 + g];
        int s2 = perm[j1 + 8 + g], s3 = perm[j1 + 12 + g];
        uint4 u0 = F[s0 * 16 + c], u1 = F[s1 * 16 + c];
        uint4 u2 = F[s2 * 16 + c], u3 = F[s3 * 16 + c];
        accu(a1, u0); accu(a1, u1); accu(a1, u2); accu(a1, u3);
        j1 += 16;
    }

    // dual single-chain fast path: 12 perm loads, clamp, 12 feat loads
    int pm0[6], pm1[6];
#pragma unroll
    for (int k = 0; k < 6; k++) pm0[k] = perm[j0 + 4 * k + g];
#pragma unroll
    for (int k = 0; k < 6; k++) pm1[k] = perm[j1 + 4 * k + g];
#pragma unroll
    for (int k = 0; k < 6; k++) if (j0 + 4 * k + g >= je0) pm0[k] = ZROW;
#pragma unroll
    for (int k = 0; k < 6; k++) if (j1 + 4 * k + g >= je1) pm1[k] = ZROW;
    uint4 u0[6], u1[6];
#pragma unroll
    for (int k = 0; k < 6; k++) u0[k] = F[pm0[k] * 16 + c];
#pragma unroll
    for (int k = 0; k < 6; k++) u1[k] = F[pm1[k] * 16 + c];
#pragma unroll
    for (int k = 0; k < 6; k++) accu(a0, u0[k]);
#pragma unroll
    for (int k = 0; k < 6; k++) accu(a1, u1[k]);

    // combine the 4 group partials for both nodes
#pragma unroll
    for (int k = 0; k < 4; k++) {
        a0[k][0] += __shfl_xor(a0[k][0], 16);
        a0[k][1] += __shfl_xor(a0[k][1], 16);
        a0[k][0] += __shfl_xor(a0[k][0], 32);
        a0[k][1] += __shfl_xor(a0[k][1], 32);
        a1[k][0] += __shfl_xor(a1[k][0], 16);
        a1[k][1] += __shfl_xor(a1[k][1], 16);
        a1[k][0] += __shfl_xor(a1[k][0], 32);
        a1[k][1] += __shfl_xor(a1[k][1], 32);
    }

    // h = x + agg
    a0[0] += up2(xv0.x); a0[1] += up2(xv0.y); a0[2] += up2(xv0.z); a0[3] += up2(xv0.w);
    a1[0] += up2(xv1.x); a1[1] += up2(xv1.y); a1[2] += up2(xv1.z); a1[3] += up2(xv1.w);

    if (g == 0) {
        uint4 r;
        r.x = ((unsigned int)f2bf(a0[0][1]) << 16) | f2bf(a0[0][0]);
        r.y = ((unsigned int)f2bf(a0[1][1]) << 16) | f2bf(a0[1][0]);
        r.z = ((unsigned int)f2bf(a0[2][1]) << 16) | f2bf(a0[2][0]);
        r.w = ((unsigned int)f2bf(a0[3][1]) << 16) | f2bf(a0[3][0]);
        ((uint4*)out)[i0 * 16 + c] = r;
    } else if (g == 1) {
        uint4 r;
        r.x = ((unsigned int)f2bf(a1[0][1]) << 16) | f2bf(a1[0][0]);
        r.y = ((unsigned int)f2bf(a1[1][1]) << 16) | f2bf(a1[1][0]);
        r.z = ((unsigned int)f2bf(a1[2][1]) << 16) | f2bf(a1[2][0]);
        r.w = ((unsigned int)f2bf(a1[3][1]) << 16) | f2bf(a1[3][0]);
        ((uint4*)out)[(i0 + 1) * 16 + c] = r;
    }
}

// ---------------- persistent register-resident-B GEMM: C = relu(A@W + bias).
__global__ __launch_bounds__(256, 2) void k_gemm_rb(const unsigned short* __restrict__ A,
                                                    const unsigned short* __restrict__ WT,
                                                    const float* __restrict__ bias,
                                                    unsigned short* __restrict__ out) {
    int gw = blockIdx.x * 4 + (threadIdx.x >> 6);   // global wave id
    int lane = threadIdx.x & 63;
    int m = lane & 15, quad = lane >> 4;

    bf16x8 bfr[8][4];
#pragma unroll
    for (int nt = 0; nt < 8; nt++) {
        const unsigned short* Bb = WT + (nt * 16 + m) * DF + quad * 8;
#pragma unroll
        for (int ks = 0; ks < 4; ks++)
            bfr[nt][ks] = *(const bf16x8*)(Bb + ks * 32);
    }
    float bv[8];
#pragma unroll
    for (int nt = 0; nt < 8; nt++) bv[nt] = bias[nt * 16 + m];

    for (int tile = gw; tile < NNODES / 16; tile += GEMM_WAVES) {
        int r0 = tile * 16;
        const unsigned short* Ab = A + (r0 + m) * DF + quad * 8;
        bf16x8 a[4];
#pragma unroll
        for (int ks = 0; ks < 4; ks++) a[ks] = *(const bf16x8*)(Ab + ks * 32);

        f32x4 acc[8];
#pragma unroll
        for (int nt = 0; nt < 8; nt++) acc[nt] = (f32x4){0.f, 0.f, 0.f, 0.f};
#pragma unroll
        for (int nt = 0; nt < 8; nt++)
#pragma unroll
            for (int ks = 0; ks < 4; ks++)
                acc[nt] = __builtin_amdgcn_mfma_f32_16x16x32_bf16(a[ks], bfr[nt][ks], acc[nt], 0, 0, 0);

#pragma unroll
        for (int nt = 0; nt < 8; nt++) {
            int col = nt * 16 + m;
#pragma unroll
            for (int reg = 0; reg < 4; reg++) {
                int row = r0 + quad * 4 + reg;
                float v = acc[nt][reg] + bv[nt];
                if (v < 0.f) v = 0.f;
                out[row * DF + col] = f2bf(v);
            }
        }
    }
}

// ---------------- persistent fc (128 -> 40, padded 48) + fused log_softmax.
__global__ __launch_bounds__(256, 2) void k_fc_rb(const unsigned short* __restrict__ A,
                                                  const unsigned short* __restrict__ WfcT,
                                                  const float* __restrict__ bfc,
                                                  const int* __restrict__ flags,
                                                  void* __restrict__ out) {
    int gw = blockIdx.x * 4 + (threadIdx.x >> 6);
    int lane = threadIdx.x & 63;
    int m = lane & 15, quad = lane >> 4;
    bool valid2 = (m < 8);
    int obf = flags[1];

    bf16x8 bfr[3][4];
#pragma unroll
    for (int nt = 0; nt < 3; nt++) {
        const unsigned short* Bb = WfcT + (nt * 16 + m) * DF + quad * 8;
#pragma unroll
        for (int ks = 0; ks < 4; ks++)
            bfr[nt][ks] = *(const bf16x8*)(Bb + ks * 32);
    }
    float bv0 = bfc[m], bv1 = bfc[16 + m];
    float bv2 = valid2 ? bfc[32 + m] : 0.f;

    for (int tile = gw; tile < NNODES / 16; tile += GEMM_WAVES) {
        int r0 = tile * 16;
        const unsigned short* Ab = A + (r0 + m) * DF + quad * 8;
        bf16x8 a[4];
#pragma unroll
        for (int ks = 0; ks < 4; ks++) a[ks] = *(const bf16x8*)(Ab + ks * 32);

        f32x4 acc[3];
#pragma unroll
        for (int nt = 0; nt < 3; nt++) acc[nt] = (f32x4){0.f, 0.f, 0.f, 0.f};
#pragma unroll
        for (int nt = 0; nt < 3; nt++)
#pragma unroll
            for (int ks = 0; ks < 4; ks++)
                acc[nt] = __builtin_amdgcn_mfma_f32_16x16x32_bf16(a[ks], bfr[nt][ks], acc[nt], 0, 0, 0);

#pragma unroll
        for (int reg = 0; reg < 4; reg++) {
            float v0 = acc[0][reg] + bv0;
            float v1 = acc[1][reg] + bv1;
            float v2 = valid2 ? (acc[2][reg] + bv2) : -3.0e38f;
            float mx = fmaxf(fmaxf(v0, v1), v2);
#pragma unroll
            for (int off = 1; off < 16; off <<= 1) mx = fmaxf(mx, __shfl_xor(mx, off, 16));
            float e = __expf(v0 - mx) + __expf(v1 - mx) + (valid2 ? __expf(v2 - mx) : 0.f);
#pragma unroll
            for (int off = 1; off < 16; off <<= 1) e += __shfl_xor(e, off, 16);
            float l = mx + __logf(e);
            int row = r0 + quad * 4 + reg;
            if (obf) {
                unsigned short* o = (unsigned short*)out + row * NC;
                o[m] = f2bf(v0 - l);
                o[16 + m] = f2bf(v1 - l);
                if (valid2) o[32 + m] = f2bf(v2 - l);
            } else {
                float* o = (float*)out + row * NC;
                o[m] = v0 - l;
                o[16 + m] = v1 - l;
                if (valid2) o[32 + m] = v2 - l;
            }
        }
    }
}

extern "C" void kernel_launch(void* const* d_in, const int* in_sizes, int n_in,
                              void* d_out, int out_size, void* d_ws, size_t ws_size,
                              hipStream_t stream) {
    const void* x   = d_in[0];
    const void* ei  = d_in[1];
    const void* w1a = d_in[2];
    const void* b1a = d_in[3];
    const void* w1b = d_in[4];
    const void* b1b = d_in[5];
    const void* w2a = d_in[6];
    const void* b2a = d_in[7];
    const void* w2b = d_in[8];
    const void* b2b = d_in[9];
    const void* wfc = d_in[10];
    const void* bfc = d_in[11];

    char* ws = (char*)d_ws;
    size_t off = 0;
    auto alloc = [&](size_t bytes) {
        void* p = ws + off;
        off += (bytes + 255) & ~(size_t)255;
        return p;
    };
    // B0/B1 have one extra zeroed row (ZROW) for the gather's slot clamp.
    unsigned short* B0    = (unsigned short*)alloc((size_t)(NNODES + 1) * DF * 2);
    unsigned short* B1    = (unsigned short*)alloc((size_t)(NNODES + 1) * DF * 2);
    unsigned short* B2    = (unsigned short*)alloc((size_t)NNODES * DF * 2);
    int2*           ebin  = (int2*)alloc((size_t)NEDGES * 8);
    int*            perm  = (int*)alloc((size_t)(NEDGES + 64) * 4);   // +64 pad: slot over-read
    int*            rowptr= (int*)alloc((size_t)(NNODES + 1) * 4);
    int*            binCnt= (int*)alloc(NB * 4);
    int*            binOfs= (int*)alloc((NB + 1) * 4);
    int*            binCur= (int*)alloc(NB * 4);
    int*            flags = (int*)alloc(256);
    unsigned short* wAll  = (unsigned short*)alloc((4 * 16384 + NCP * 128) * 2);
    float*          bAll  = (float*)alloc((512 + NC) * 4);

    unsigned short* w1aT = wAll;
    unsigned short* w1bT = wAll + 16384;
    unsigned short* w2aT = wAll + 32768;
    unsigned short* w2bT = wAll + 49152;
    unsigned short* wfcT = wAll + 65536;
    float* b1af = bAll;
    float* b1bf = bAll + 128;
    float* b2af = bAll + 256;
    float* b2bf = bAll + 384;
    float* bfcf = bAll + 512;

    // ---- dtype detection (+ binCnt zero) + canonicalization
    k_detect<<<1, 256, 0, stream>>>((const unsigned int*)ei, (const unsigned int*)x, flags, binCnt);
    k_cvt_feat<<<NNODES * DF / (256 * 8), 256, 0, stream>>>(x, flags, B0);   // 6250 blocks

    int wprepN = 4 * 16384 + NCP * 128 + 512 + NC + 512;
    k_wprep<<<(wprepN + 255) / 256, 256, 0, stream>>>(w1a, w1b, w2a, w2b, wfc,
                                                      b1a, b1b, b2a, b2b, bfc,
                                                      flags, wAll, bAll,
                                                      B0 + (size_t)NNODES * DF,
                                                      B1 + (size_t)NNODES * DF);

    // ---- binned CSR build (reads edge_index directly)
    int nEB = (NEDGES + CH - 1) / CH;                          // 391
    k_bincount<<<nEB, 256, 0, stream>>>(ei, flags, binCnt);
    k_binscan<<<1, 256, 0, stream>>>(binCnt, binOfs, binCur);
    k_binscatter<<<nEB, 256, 0, stream>>>(ei, flags, binCur, ebin);
    k_binfill<<<NB, 256, 0, stream>>>(ebin, binOfs, rowptr, perm);

    const int gatherGrid = NNODES / 8;                         // 12500 (2 nodes/wave)

    // ---- layer 1
    k_gather<<<gatherGrid, 256, 0, stream>>>(B0, B0, rowptr, perm, B1);
    k_gemm_rb<<<GEMM_BLOCKS, 256, 0, stream>>>(B1, w1aT, b1af, B2);
    k_gemm_rb<<<GEMM_BLOCKS, 256, 0, stream>>>(B2, w1bT, b1bf, B1);   // h1 -> B1

    // ---- layer 2
    k_gather<<<gatherGrid, 256, 0, stream>>>(B1, B1, rowptr, perm, B2);
    k_gemm_rb<<<GEMM_BLOCKS, 256, 0, stream>>>(B2, w2aT, b2af, B0);
    k_gemm_rb<<<GEMM_BLOCKS, 256, 0, stream>>>(B0, w2bT, b2bf, B2);   // h2 -> B2

    // ---- fc + log_softmax
    k_fc_rb<<<GEMM_BLOCKS, 256, 0, stream>>>(B2, wfcT, bfcf, flags, d_out);
}

// Round 6
// 367.065 us; speedup vs baseline: 1.1390x; 1.0218x over previous
//
#include <hip/hip_runtime.h>
#include <hip/hip_bf16.h>

#define NNODES 100000
#define NEDGES 1600000
#define DF 128
#define NC 40
#define NCP 48          // padded fc cols (3 x 16)
#define NB 196          // CSR bins: dst>>9, 512 nodes/bin
#define CH 4096         // edges per binscatter/bincount block
#define MLP_BLOCKS 256  // fused MLP: 1 block/CU (1 wave/SIMD at ~340-400 VGPR)
#define MLP_WAVES (MLP_BLOCKS * 4)
#define ZROW NNODES     // zero feature row appended to B0/B1

typedef __bf16 bf16x8 __attribute__((ext_vector_type(8)));
typedef float f32x4 __attribute__((ext_vector_type(4)));
typedef float f32x2 __attribute__((ext_vector_type(2)));

__device__ __forceinline__ unsigned short f2bf(float f) {
    unsigned int u = __builtin_bit_cast(unsigned int, f);
    u = (u + 0x7FFFu + ((u >> 16) & 1u)) >> 16;   // RNE
    return (unsigned short)u;
}
__device__ __forceinline__ float bf2f(unsigned short s) {
    unsigned int u = ((unsigned int)s) << 16;
    return __builtin_bit_cast(float, u);
}
__device__ __forceinline__ float bfLo(unsigned int u) {
    return __builtin_bit_cast(float, u << 16);
}
__device__ __forceinline__ float bfHi(unsigned int u) {
    return __builtin_bit_cast(float, u & 0xFFFF0000u);
}
__device__ __forceinline__ f32x2 up2(unsigned int u) {
    return (f32x2){bfLo(u), bfHi(u)};
}

// ---------------- dtype detection (flags[0]: ei is int64; flags[1]: floats are bf16)
// also zeroes binCnt (fused memset).
__global__ void k_detect(const unsigned int* __restrict__ ei32,
                         const unsigned int* __restrict__ x32,
                         int* __restrict__ flags,
                         int* __restrict__ binCnt) {
    __shared__ unsigned int rOr[256];
    __shared__ int rCnt[256];
    for (int i = threadIdx.x; i < NB; i += 256) binCnt[i] = 0;
    unsigned int o = 0; int c = 0;
    for (int i = threadIdx.x; i < 1024; i += 256) o |= ei32[2 * i + 1];
    for (int i = threadIdx.x; i < 4096; i += 256) {
        unsigned int e = (x32[i] >> 7) & 0xFFu;
        c += (e >= 100u && e <= 140u) ? 1 : 0;
    }
    rOr[threadIdx.x] = o; rCnt[threadIdx.x] = c;
    __syncthreads();
    for (int s = 128; s; s >>= 1) {
        if ((int)threadIdx.x < s) {
            rOr[threadIdx.x] |= rOr[threadIdx.x + s];
            rCnt[threadIdx.x] += rCnt[threadIdx.x + s];
        }
        __syncthreads();
    }
    if (threadIdx.x == 0) {
        flags[0] = (rOr[0] == 0u) ? 1 : 0;
        flags[1] = (rCnt[0] > 2457) ? 1 : 0;
    }
}

__device__ __forceinline__ int ldIdx(const void* ei, int flag64, int i) {
    return flag64 ? (int)((const long long*)ei)[i] : ((const int*)ei)[i];
}

// ---------------- features -> canonical bf16, 8 elems/thread (vectorized)
__global__ __launch_bounds__(256) void k_cvt_feat(const void* __restrict__ src,
                                                  const int* __restrict__ flags,
                                                  unsigned short* __restrict__ dst) {
    int i = blockIdx.x * 256 + threadIdx.x;   // 6250 blocks: i < 1.6M, 8 elems each
    if (flags[1]) {
        ((uint4*)dst)[i] = ((const uint4*)src)[i];
    } else {
        uint4 a = ((const uint4*)src)[2 * i];
        uint4 b = ((const uint4*)src)[2 * i + 1];
        auto pk = [](unsigned int lo, unsigned int hi) -> unsigned int {
            return ((unsigned int)f2bf(__builtin_bit_cast(float, hi)) << 16) |
                   f2bf(__builtin_bit_cast(float, lo));
        };
        uint4 r;
        r.x = pk(a.x, a.y);
        r.y = pk(a.z, a.w);
        r.z = pk(b.x, b.y);
        r.w = pk(b.z, b.w);
        ((uint4*)dst)[i] = r;
    }
}

// ---------------- all weights (transposed bf16) + biases (fp32) + zero-row pads.
__global__ __launch_bounds__(256) void k_wprep(const void* w1a, const void* w1b,
                                               const void* w2a, const void* w2b,
                                               const void* wfc,
                                               const void* b1a, const void* b1b,
                                               const void* b2a, const void* b2b,
                                               const void* bfc,
                                               const int* __restrict__ flags,
                                               unsigned short* __restrict__ wAll,
                                               float* __restrict__ bAll,
                                               unsigned short* __restrict__ pad0,
                                               unsigned short* __restrict__ pad1) {
    int idx = blockIdx.x * 256 + threadIdx.x;
    int bf = flags[1];
    auto ldf = [&](const void* p, int i) -> float {
        return bf ? bf2f(((const unsigned short*)p)[i]) : ((const float*)p)[i];
    };
    if (idx < 65536) {                       // 4 square transposes
        int wi = idx >> 14, r = idx & 16383;
        int n = r >> 7, k = r & 127;
        const void* s = (wi == 0) ? w1a : (wi == 1) ? w1b : (wi == 2) ? w2a : w2b;
        wAll[idx] = f2bf(ldf(s, k * 128 + n));
    } else if (idx < 65536 + NCP * 128) {    // wfc transpose, zero pad
        int r = idx - 65536;
        int n = r >> 7, k = r & 127;
        wAll[idx] = (n < NC) ? f2bf(ldf(wfc, k * NC + n)) : (unsigned short)0;
    } else if (idx < 65536 + NCP * 128 + 512 + NC) {
        int r = idx - (65536 + NCP * 128);
        const void* s; int i;
        if (r < 128)      { s = b1a; i = r; }
        else if (r < 256) { s = b1b; i = r - 128; }
        else if (r < 384) { s = b2a; i = r - 256; }
        else if (r < 512) { s = b2b; i = r - 384; }
        else              { s = bfc; i = r - 512; }
        bAll[r] = ldf(s, i);
    } else if (idx < 65536 + NCP * 128 + 512 + NC + 256) {
        pad0[idx - (65536 + NCP * 128 + 512 + NC)] = 0;   // B0 zero row
    } else if (idx < 65536 + NCP * 128 + 512 + NC + 512) {
        pad1[idx - (65536 + NCP * 128 + 512 + NC + 256)] = 0;  // B1 zero row
    }
}

// ================= binned CSR build =================
__global__ __launch_bounds__(256) void k_bincount(const void* __restrict__ ei,
                                                  const int* __restrict__ flags,
                                                  int* __restrict__ binCnt) {
    __shared__ int l[NB];
    int t = threadIdx.x;
    int f64 = flags[0];
    for (int i = t; i < NB; i += 256) l[i] = 0;
    __syncthreads();
    int base = blockIdx.x * CH;
#pragma unroll
    for (int k = 0; k < CH / 256; k++) {
        int e = base + k * 256 + t;
        if (e < NEDGES) atomicAdd(&l[ldIdx(ei, f64, NEDGES + e) >> 9], 1);
    }
    __syncthreads();
    for (int i = t; i < NB; i += 256)
        if (l[i]) atomicAdd(&binCnt[i], l[i]);
}

__global__ __launch_bounds__(256) void k_binscan(const int* __restrict__ binCnt,
                                                 int* __restrict__ binOfs,
                                                 int* __restrict__ binCur) {
    __shared__ int sh[256];
    int t = threadIdx.x;
    int v = (t < NB) ? binCnt[t] : 0;
    sh[t] = v;
    __syncthreads();
    for (int off = 1; off < 256; off <<= 1) {
        int x = (t >= off) ? sh[t - off] : 0;
        __syncthreads();
        sh[t] += x;
        __syncthreads();
    }
    if (t < NB) {
        binOfs[t + 1] = sh[t];
        binCur[t] = sh[t] - v;      // exclusive
    }
    if (t == 0) binOfs[0] = 0;
}

__global__ __launch_bounds__(256) void k_binscatter(const void* __restrict__ ei,
                                                    const int* __restrict__ flags,
                                                    int* __restrict__ binCur,
                                                    int2* __restrict__ ebin) {
    __shared__ int lcnt[NB], lbase[NB], lofs[NB];
    int t = threadIdx.x;
    int f64 = flags[0];
    for (int i = t; i < NB; i += 256) lcnt[i] = 0;
    __syncthreads();
    int base = blockIdx.x * CH;
    int2 ed[CH / 256];
    int bn[CH / 256];
#pragma unroll
    for (int k = 0; k < CH / 256; k++) {
        int e = base + k * 256 + t;
        if (e < NEDGES) {
            ed[k].x = ldIdx(ei, f64, e);
            ed[k].y = ldIdx(ei, f64, NEDGES + e);
            bn[k] = ed[k].y >> 9;
            atomicAdd(&lcnt[bn[k]], 1);
        } else bn[k] = -1;
    }
    __syncthreads();
    if (t < NB) {
        int c = lcnt[t];
        lbase[t] = c ? atomicAdd(&binCur[t], c) : 0;
        lofs[t] = 0;
    }
    __syncthreads();
#pragma unroll
    for (int k = 0; k < CH / 256; k++) {
        if (bn[k] >= 0) {
            int p = lbase[bn[k]] + atomicAdd(&lofs[bn[k]], 1);
            ebin[p] = ed[k];
        }
    }
}

__global__ __launch_bounds__(256) void k_binfill(const int2* __restrict__ ebin,
                                                 const int* __restrict__ binOfs,
                                                 int* __restrict__ rowptr,
                                                 int* __restrict__ perm) {
    __shared__ int deg[512], lptr[512], ssum[256];
    int b = blockIdx.x, t = threadIdx.x;
    int n0 = b << 9;
    int nn = NNODES - n0; if (nn > 512) nn = 512;
    int e0 = binOfs[b], e1 = binOfs[b + 1];
    deg[t] = 0; deg[t + 256] = 0;
    __syncthreads();
    for (int e = e0 + t; e < e1; e += 256)
        atomicAdd(&deg[ebin[e].y - n0], 1);
    __syncthreads();
    int d0 = deg[2 * t], d1 = deg[2 * t + 1];
    int s = d0 + d1;
    ssum[t] = s;
    __syncthreads();
    for (int off = 1; off < 256; off <<= 1) {
        int x = (t >= off) ? ssum[t - off] : 0;
        __syncthreads();
        ssum[t] += x;
        __syncthreads();
    }
    int ex = ssum[t] - s;
    lptr[2 * t] = ex;
    lptr[2 * t + 1] = ex + d0;
    if (2 * t < nn)     rowptr[n0 + 2 * t] = e0 + ex;
    if (2 * t + 1 < nn) rowptr[n0 + 2 * t + 1] = e0 + ex + d0;
    if (b == NB - 1 && t == 0) rowptr[NNODES] = e1;
    deg[2 * t] = 0; deg[2 * t + 1] = 0;   // reuse as cursor
    __syncthreads();
    for (int e = e0 + t; e < e1; e += 256) {
        int2 ed = ebin[e];
        int d = ed.y - n0;
        int pos = e0 + lptr[d] + atomicAdd(&deg[d], 1);
        perm[pos] = ed.x;
    }
}

// ================= gather aggregation (R4 best: 57.0us) =================
// One node per wave; 4 groups of 16 lanes; lane (g,c) loads dwordx4 of one
// source row. Degree-bucketed straight-line paths (2/4/6 slots, wave-uniform
// branch); out-of-range slots value-clamp the loaded perm to ZROW (zero row)
// -> unconditional accumulate. At the random-row pattern ceiling (~3.7 TB/s
// miss-path; R5 falsified the concurrency hypothesis).
__device__ __forceinline__ void accu(f32x2* acc, uint4 u) {
    acc[0] += up2(u.x);
    acc[1] += up2(u.y);
    acc[2] += up2(u.z);
    acc[3] += up2(u.w);
}

template <int S>
__device__ __forceinline__ void gslots(const int* __restrict__ perm, const uint4* __restrict__ F,
                                       int j, int je, int g, int c, f32x2* acc) {
    int pm[S];
#pragma unroll
    for (int k = 0; k < S; k++) pm[k] = perm[j + 4 * k + g];
#pragma unroll
    for (int k = 0; k < S; k++)
        if (j + 4 * k + g >= je) pm[k] = ZROW;       // value-clamp, off the addr-issue path
    uint4 u[S];
#pragma unroll
    for (int k = 0; k < S; k++) u[k] = F[pm[k] * 16 + c];
#pragma unroll
    for (int k = 0; k < S; k++) accu(acc, u[k]);
}

__global__ __launch_bounds__(256) void k_gather(const unsigned short* __restrict__ feat,
                                                const unsigned short* __restrict__ x,
                                                const int* __restrict__ rowptr,
                                                const int* __restrict__ perm,
                                                unsigned short* __restrict__ out) {
    int wave = threadIdx.x >> 6, lane = threadIdx.x & 63;
    int i = blockIdx.x * 4 + wave;        // NNODES = 25000*4 exactly
    int g = lane >> 4, c = lane & 15;
    const uint4* F = (const uint4*)feat;  // one row = 16 uint4

    // independent head loads first: x row + rowptr (overlap whole chain)
    uint4 xv = ((const uint4*)x)[i * 16 + c];
    int jb = rowptr[i], je = rowptr[i + 1];

    f32x2 acc[4];
#pragma unroll
    for (int k = 0; k < 4; k++) acc[k] = (f32x2){0.f, 0.f};

    int j = jb;
    // rare slow path (deg > 24, ~2.2%): peel 16-edge chunks (all-valid, unconditional)
    while (je - j > 24) {
        int s0 = perm[j + g], s1 = perm[j + 4 + g];
        int s2 = perm[j + 8 + g], s3 = perm[j + 12 + g];
        uint4 u0 = F[s0 * 16 + c];
        uint4 u1 = F[s1 * 16 + c];
        uint4 u2 = F[s2 * 16 + c];
        uint4 u3 = F[s3 * 16 + c];
        accu(acc, u0); accu(acc, u1); accu(acc, u2); accu(acc, u3);
        j += 16;
    }
    int deg = je - j;                     // 0..24, wave-uniform
    if (deg > 16)      gslots<6>(perm, F, j, je, g, c, acc);
    else if (deg > 8)  gslots<4>(perm, F, j, je, g, c, acc);
    else if (deg > 0)  gslots<2>(perm, F, j, je, g, c, acc);

    // combine the 4 group partials
#pragma unroll
    for (int k = 0; k < 4; k++) {
        acc[k][0] += __shfl_xor(acc[k][0], 16);
        acc[k][1] += __shfl_xor(acc[k][1], 16);
        acc[k][0] += __shfl_xor(acc[k][0], 32);
        acc[k][1] += __shfl_xor(acc[k][1], 32);
    }

    // h = x + agg
    acc[0] += up2(xv.x);
    acc[1] += up2(xv.y);
    acc[2] += up2(xv.z);
    acc[3] += up2(xv.w);

    if (g == 0) {
        uint4 r;
        r.x = ((unsigned int)f2bf(acc[0][1]) << 16) | f2bf(acc[0][0]);
        r.y = ((unsigned int)f2bf(acc[1][1]) << 16) | f2bf(acc[1][0]);
        r.z = ((unsigned int)f2bf(acc[2][1]) << 16) | f2bf(acc[2][0]);
        r.w = ((unsigned int)f2bf(acc[3][1]) << 16) | f2bf(acc[3][0]);
        ((uint4*)out)[i * 16 + c] = r;
    }
}

// ================= fused GIN MLP: out = relu(relu(A@Wa+ba)@Wb+bb) =================
// Both weights register-resident (128+128 VGPR). Per 16-row tile: 4 A-loads,
// 32 MFMA (Wa), relu -> wave-private LDS redistribute (D-layout -> A-layout,
// 16x136 u16, chunk ^= (row>>3)<<2 swizzle: ds_read_b128 bank-optimal) ->
// 32 MFMA (Wb), relu. DOFC: second LDS roundtrip + 12 MFMA (wfc) + log_softmax,
// h2 never touches global. Same-wave LDS dep: lgkmcnt only (no barriers).
// ~340/~400 VGPR -> 1 wave/SIMD; still memory-bound (per-wave serial demand
// 1024 waves x 4KB/480ns > 8 TB/s).
// Layouts (m89/m91): A[m=lane&15][k=quad*8+j]; B[k][n=lane&15]; D: col=lane&15,
// row=quad*4+reg.
template <bool DOFC>
__global__ __launch_bounds__(256, 1) void k_mlp_rb(const unsigned short* __restrict__ A,
                                                   const unsigned short* __restrict__ WaT,
                                                   const float* __restrict__ ba,
                                                   const unsigned short* __restrict__ WbT,
                                                   const float* __restrict__ bb,
                                                   const unsigned short* __restrict__ WfcT,
                                                   const float* __restrict__ bfc,
                                                   const int* __restrict__ flags,
                                                   unsigned short* __restrict__ outH,
                                                   void* __restrict__ outFC) {
    __shared__ __align__(16) unsigned short smem[4 * 2176];   // 4 waves x 16 rows x 136 u16
    int wave = threadIdx.x >> 6, lane = threadIdx.x & 63;
    int gw = blockIdx.x * 4 + wave;
    int m = lane & 15, quad = lane >> 4;
    unsigned short* T = smem + wave * 2176;

    bf16x8 wa[8][4], wb[8][4];
#pragma unroll
    for (int nt = 0; nt < 8; nt++) {
        const unsigned short* Ba = WaT + (nt * 16 + m) * DF + quad * 8;
        const unsigned short* Bb = WbT + (nt * 16 + m) * DF + quad * 8;
#pragma unroll
        for (int ks = 0; ks < 4; ks++) {
            wa[nt][ks] = *(const bf16x8*)(Ba + ks * 32);
            wb[nt][ks] = *(const bf16x8*)(Bb + ks * 32);
        }
    }
    float bva[8], bvb[8];
#pragma unroll
    for (int nt = 0; nt < 8; nt++) { bva[nt] = ba[nt * 16 + m]; bvb[nt] = bb[nt * 16 + m]; }

    bf16x8 wf[3][4];
    float fv0 = 0.f, fv1 = 0.f, fv2 = 0.f;
    bool valid2 = (m < 8);
    int obf = 0;
    if (DOFC) {
#pragma unroll
        for (int nt = 0; nt < 3; nt++) {
            const unsigned short* Bf = WfcT + (nt * 16 + m) * DF + quad * 8;
#pragma unroll
            for (int ks = 0; ks < 4; ks++) wf[nt][ks] = *(const bf16x8*)(Bf + ks * 32);
        }
        fv0 = bfc[m]; fv1 = bfc[16 + m];
        fv2 = valid2 ? bfc[32 + m] : 0.f;
        obf = flags[1];
    }

    // swizzled u16 index within the 16x136 tile
    auto ladr = [](int row, int col) -> int {
        int chunk = (col >> 3) ^ ((row >> 3) << 2);
        return row * 136 + chunk * 8 + (col & 7);
    };

    for (int tile = gw; tile < NNODES / 16; tile += MLP_WAVES) {
        int r0 = tile * 16;
        const unsigned short* Ab = A + (r0 + m) * DF + quad * 8;
        bf16x8 a[4];
#pragma unroll
        for (int ks = 0; ks < 4; ks++) a[ks] = *(const bf16x8*)(Ab + ks * 32);

        f32x4 acc[8];
#pragma unroll
        for (int nt = 0; nt < 8; nt++) acc[nt] = (f32x4){0.f, 0.f, 0.f, 0.f};
#pragma unroll
        for (int nt = 0; nt < 8; nt++)
#pragma unroll
            for (int ks = 0; ks < 4; ks++)
                acc[nt] = __builtin_amdgcn_mfma_f32_16x16x32_bf16(a[ks], wa[nt][ks], acc[nt], 0, 0, 0);

        // stage-1 epilogue -> LDS (relu'd bf16, D-layout value (quad*4+reg, nt*16+m))
#pragma unroll
        for (int nt = 0; nt < 8; nt++)
#pragma unroll
            for (int reg = 0; reg < 4; reg++) {
                float v = acc[nt][reg] + bva[nt];
                if (v < 0.f) v = 0.f;
                T[ladr(quad * 4 + reg, nt * 16 + m)] = f2bf(v);
            }

        // stage-2: read A-frags back (lane m = row m)
        bf16x8 a2[4];
#pragma unroll
        for (int ks = 0; ks < 4; ks++) {
            int chunk = (ks * 4 + quad) ^ ((m >> 3) << 2);
            a2[ks] = *(const bf16x8*)&T[m * 136 + chunk * 8];
        }
#pragma unroll
        for (int nt = 0; nt < 8; nt++) acc[nt] = (f32x4){0.f, 0.f, 0.f, 0.f};
#pragma unroll
        for (int nt = 0; nt < 8; nt++)
#pragma unroll
            for (int ks = 0; ks < 4; ks++)
                acc[nt] = __builtin_amdgcn_mfma_f32_16x16x32_bf16(a2[ks], wb[nt][ks], acc[nt], 0, 0, 0);

        if (!DOFC) {
#pragma unroll
            for (int nt = 0; nt < 8; nt++) {
                int col = nt * 16 + m;
#pragma unroll
                for (int reg = 0; reg < 4; reg++) {
                    int row = r0 + quad * 4 + reg;
                    float v = acc[nt][reg] + bvb[nt];
                    if (v < 0.f) v = 0.f;
                    outH[row * DF + col] = f2bf(v);
                }
            }
        } else {
            // h2 -> LDS (after stage-2 reads: same-wave DS ops are in-order)
#pragma unroll
            for (int nt = 0; nt < 8; nt++)
#pragma unroll
                for (int reg = 0; reg < 4; reg++) {
                    float v = acc[nt][reg] + bvb[nt];
                    if (v < 0.f) v = 0.f;
                    T[ladr(quad * 4 + reg, nt * 16 + m)] = f2bf(v);
                }
            bf16x8 a3[4];
#pragma unroll
            for (int ks = 0; ks < 4; ks++) {
                int chunk = (ks * 4 + quad) ^ ((m >> 3) << 2);
                a3[ks] = *(const bf16x8*)&T[m * 136 + chunk * 8];
            }
            f32x4 fa[3];
#pragma unroll
            for (int nt = 0; nt < 3; nt++) fa[nt] = (f32x4){0.f, 0.f, 0.f, 0.f};
#pragma unroll
            for (int nt = 0; nt < 3; nt++)
#pragma unroll
                for (int ks = 0; ks < 4; ks++)
                    fa[nt] = __builtin_amdgcn_mfma_f32_16x16x32_bf16(a3[ks], wf[nt][ks], fa[nt], 0, 0, 0);

#pragma unroll
            for (int reg = 0; reg < 4; reg++) {
                float v0 = fa[0][reg] + fv0;
                float v1 = fa[1][reg] + fv1;
                float v2 = valid2 ? (fa[2][reg] + fv2) : -3.0e38f;
                float mx = fmaxf(fmaxf(v0, v1), v2);
#pragma unroll
                for (int off = 1; off < 16; off <<= 1) mx = fmaxf(mx, __shfl_xor(mx, off, 16));
                float e = __expf(v0 - mx) + __expf(v1 - mx) + (valid2 ? __expf(v2 - mx) : 0.f);
#pragma unroll
                for (int off = 1; off < 16; off <<= 1) e += __shfl_xor(e, off, 16);
                float l = mx + __logf(e);
                int row = r0 + quad * 4 + reg;
                if (obf) {
                    unsigned short* o = (unsigned short*)outFC + row * NC;
                    o[m] = f2bf(v0 - l);
                    o[16 + m] = f2bf(v1 - l);
                    if (valid2) o[32 + m] = f2bf(v2 - l);
                } else {
                    float* o = (float*)outFC + row * NC;
                    o[m] = v0 - l;
                    o[16 + m] = v1 - l;
                    if (valid2) o[32 + m] = v2 - l;
                }
            }
        }
    }
}

extern "C" void kernel_launch(void* const* d_in, const int* in_sizes, int n_in,
                              void* d_out, int out_size, void* d_ws, size_t ws_size,
                              hipStream_t stream) {
    const void* x   = d_in[0];
    const void* ei  = d_in[1];
    const void* w1a = d_in[2];
    const void* b1a = d_in[3];
    const void* w1b = d_in[4];
    const void* b1b = d_in[5];
    const void* w2a = d_in[6];
    const void* b2a = d_in[7];
    const void* w2b = d_in[8];
    const void* b2b = d_in[9];
    const void* wfc = d_in[10];
    const void* bfc = d_in[11];

    char* ws = (char*)d_ws;
    size_t off = 0;
    auto alloc = [&](size_t bytes) {
        void* p = ws + off;
        off += (bytes + 255) & ~(size_t)255;
        return p;
    };
    // B0/B1 have one extra zeroed row (ZROW) for the gather's slot clamp.
    unsigned short* B0    = (unsigned short*)alloc((size_t)(NNODES + 1) * DF * 2);
    unsigned short* B1    = (unsigned short*)alloc((size_t)(NNODES + 1) * DF * 2);
    int2*           ebin  = (int2*)alloc((size_t)NEDGES * 8);
    int*            perm  = (int*)alloc((size_t)(NEDGES + 64) * 4);   // +64 pad: slot over-read
    int*            rowptr= (int*)alloc((size_t)(NNODES + 1) * 4);
    int*            binCnt= (int*)alloc(NB * 4);
    int*            binOfs= (int*)alloc((NB + 1) * 4);
    int*            binCur= (int*)alloc(NB * 4);
    int*            flags = (int*)alloc(256);
    unsigned short* wAll  = (unsigned short*)alloc((4 * 16384 + NCP * 128) * 2);
    float*          bAll  = (float*)alloc((512 + NC) * 4);

    unsigned short* w1aT = wAll;
    unsigned short* w1bT = wAll + 16384;
    unsigned short* w2aT = wAll + 32768;
    unsigned short* w2bT = wAll + 49152;
    unsigned short* wfcT = wAll + 65536;
    float* b1af = bAll;
    float* b1bf = bAll + 128;
    float* b2af = bAll + 256;
    float* b2bf = bAll + 384;
    float* bfcf = bAll + 512;

    // ---- dtype detection (+ binCnt zero) + canonicalization
    k_detect<<<1, 256, 0, stream>>>((const unsigned int*)ei, (const unsigned int*)x, flags, binCnt);
    k_cvt_feat<<<NNODES * DF / (256 * 8), 256, 0, stream>>>(x, flags, B0);   // 6250 blocks

    int wprepN = 4 * 16384 + NCP * 128 + 512 + NC + 512;
    k_wprep<<<(wprepN + 255) / 256, 256, 0, stream>>>(w1a, w1b, w2a, w2b, wfc,
                                                      b1a, b1b, b2a, b2b, bfc,
                                                      flags, wAll, bAll,
                                                      B0 + (size_t)NNODES * DF,
                                                      B1 + (size_t)NNODES * DF);

    // ---- binned CSR build (reads edge_index directly)
    int nEB = (NEDGES + CH - 1) / CH;                          // 391
    k_bincount<<<nEB, 256, 0, stream>>>(ei, flags, binCnt);
    k_binscan<<<1, 256, 0, stream>>>(binCnt, binOfs, binCur);
    k_binscatter<<<nEB, 256, 0, stream>>>(ei, flags, binCur, ebin);
    k_binfill<<<NB, 256, 0, stream>>>(ebin, binOfs, rowptr, perm);

    const int gatherGrid = NNODES / 4;                         // 25000

    // ---- layer 1: gather -> fused MLP (h1 into B0; its ZROW pad stays zero)
    k_gather<<<gatherGrid, 256, 0, stream>>>(B0, B0, rowptr, perm, B1);
    k_mlp_rb<false><<<MLP_BLOCKS, 256, 0, stream>>>(B1, w1aT, b1af, w1bT, b1bf,
                                                    nullptr, nullptr, flags, B0, nullptr);

    // ---- layer 2: gather -> fused MLP + fc + log_softmax (h2 never hits global)
    k_gather<<<gatherGrid, 256, 0, stream>>>(B0, B0, rowptr, perm, B1);
    k_mlp_rb<true><<<MLP_BLOCKS, 256, 0, stream>>>(B1, w2aT, b2af, w2bT, b2bf,
                                                   wfcT, bfcf, flags, nullptr, d_out);
}